// Round 9
// baseline (162.811 us; speedup 1.0000x reference)
//
#include <hip/hip_runtime.h>
#include <hip/hip_bf16.h>

// ---------------------------------------------------------------------------
// PointNet Feature Propagation, MI355X (gfx950)
//   Algebra: y0 = upts@W0a^T + sum_j w_j * Z[idx_j],  Z = kpts@W0b^T
//   3-NN via 5^3 spatial grid (exact: quantized top-5 + rescue + brute fail
//   path), replacing the brute chunked scan (41us VALU floor, R6-R8).
//   KB:  bin_scatter  known pts -> [B][125][32] sentinel-padded cell table
//   KG:  nn_grid      4 thr/query scan 2x2x2 block -> top5 -> rescue -> widx
//                     fail (d3 > guarantee | cell overflow) -> fail_list
//   KF:  nn_brute     1 wave/failed query, full 2048 scan, shuffle merge
//   KZ:  zgemm        Z = bf16(kpts) @ W0b^T
//   KI:  interp_z     widx -> gather Z rows -> xz bf16
//   K1c: gemm1z, K4: gemm2, K6: bn_out  (unchanged, proven)
// ---------------------------------------------------------------------------

typedef __attribute__((ext_vector_type(8))) short short8;
typedef __attribute__((ext_vector_type(4))) float f32x4;

#define BB 8
#define NN 8192
#define SS 2048
#define M_TOT (BB * NN)      // 65536 points
#define N1DIM 256
#define K2DIM 256
#define N2DIM 128
#define BK 64

#define GDIM 5
#define NCELL (GDIM * GDIM * GDIM)   // 125
#define SLOTS 32
#define CELLW 0.2f

#define KEY_MASK 0xFFFFF800u
#define IDX_MASK 0x7FFu

__device__ __forceinline__ unsigned short f2bf(float f) {
    unsigned int x = __float_as_uint(f);
    unsigned int r = x + 0x7fffu + ((x >> 16) & 1u);  // RNE
    return (unsigned short)(r >> 16);
}
__device__ __forceinline__ float bf2f(unsigned short u) {
    return __uint_as_float(((unsigned int)u) << 16);
}
__device__ __forceinline__ unsigned int med3_u32(unsigned int a, unsigned int b,
                                                 unsigned int c) {
    unsigned int r;
    asm("v_med3_u32 %0, %1, %2, %3" : "=v"(r) : "v"(a), "v"(b), "v"(c));
    return r;
}

// insert key into sorted ascending k[0..4] (min/med3 cascade, 5 ops)
__device__ __forceinline__ void ins5(unsigned int k[5], unsigned int key) {
    unsigned int n1 = med3_u32(k[0], k[1], key);
    unsigned int n2 = med3_u32(k[1], k[2], key);
    unsigned int n3 = med3_u32(k[2], k[3], key);
    unsigned int n4 = med3_u32(k[3], k[4], key);
    k[0] = min(k[0], key);
    k[1] = n1; k[2] = n2; k[3] = n3; k[4] = n4;
}

// exact-distance rescue of quantized top-5 -> widx write; returns exact d3
// (3rd-smallest; NaN if <3 valid candidates).
__device__ __forceinline__ float rescue_write(
    const unsigned int k[5], float qx, float qy, float qz,
    const float4* __restrict__ kpB, uint4* __restrict__ widx, size_t pt)
{
    unsigned long long e[5];
#pragma unroll
    for (int i = 0; i < 5; ++i) {
        if ((k[i] & KEY_MASK) >= 0x7F800000u) {
            e[i] = 0xFFFFFFFFFFFFFFFFull;     // sentinel / inf: never wins
        } else {
            unsigned int idx = k[i] & IDX_MASK;
            float4 c = kpB[idx];
            float dx = c.x - qx, dy = c.y - qy, dz = c.z - qz;
            float d = fmaf(dx, dx, fmaf(dy, dy, dz * dz));
            e[i] = ((unsigned long long)__float_as_uint(d) << 32) | idx;
        }
    }
#pragma unroll
    for (int i = 0; i < 3; ++i)
#pragma unroll
        for (int j = i + 1; j < 5; ++j)
            if (e[j] < e[i]) { unsigned long long t = e[i]; e[i] = e[j]; e[j] = t; }

    float d0 = __uint_as_float((unsigned int)(e[0] >> 32));
    float d1 = __uint_as_float((unsigned int)(e[1] >> 32));
    float d2 = __uint_as_float((unsigned int)(e[2] >> 32));
    float r0 = 1.0f / (d0 + 1e-8f);
    float r1 = 1.0f / (d1 + 1e-8f);
    float r2 = 1.0f / (d2 + 1e-8f);
    float rs = 1.0f / (r0 + r1 + r2);
    unsigned int i0 = (unsigned int)(e[0] & IDX_MASK);
    unsigned int i1 = (unsigned int)(e[1] & IDX_MASK);
    unsigned int i2 = (unsigned int)(e[2] & IDX_MASK);
    widx[pt] = make_uint4(__float_as_uint(r0 * rs), __float_as_uint(r1 * rs),
                          i0 | (i1 << 16), i2);
    return d2;
}

// async 16B global->LDS DMA (wave-uniform LDS base + lane*16).
__device__ __forceinline__ void gload_lds16(const void* g, void* lds) {
    __builtin_amdgcn_global_load_lds(
        (const __attribute__((address_space(1))) unsigned int*)g,
        (__attribute__((address_space(3))) unsigned int*)lds, 16, 0, 0);
}

// ---------------------------------------------------------------------------
// K0: weights cvt + kpack + grid-table sentinel fill + counters zero.
// ---------------------------------------------------------------------------
__global__ __launch_bounds__(256) void cvt_w_kernel(
    const float* __restrict__ W0, const float* __restrict__ W1,
    const float* __restrict__ kxyz,
    unsigned short* __restrict__ Wa, unsigned short* __restrict__ Wb,
    unsigned short* __restrict__ Wb1, float4* __restrict__ kpack,
    float4* __restrict__ table, int* __restrict__ cnt,
    int* __restrict__ nfail, float* __restrict__ statsF)
{
    int i = blockIdx.x * 256 + threadIdx.x;
    if (blockIdx.x == 0) {
        for (int j = threadIdx.x; j < 768; j += 256) statsF[j] = 0.0f;
        if (threadIdx.x == 0) *nfail = 0;
    }
    if (i < BB * NCELL) cnt[i] = 0;
    if (i < BB * NCELL * SLOTS)
        table[i] = make_float4(1e30f, 1e30f, 1e30f, 0.0f);
    if (i < 256 * 384) {
        int o = i / 384, c = i - o * 384;
        unsigned short v = f2bf(W0[i]);
        if (c < 128) Wa[o * 128 + c] = v;
        else         Wb[o * 256 + (c - 128)] = v;
    }
    if (i < N2DIM * K2DIM) Wb1[i] = f2bf(W1[i]);
    if (i < BB * SS) {
        const float* p = kxyz + (size_t)i * 3;
        float px = p[0], py = p[1], pz = p[2];
        kpack[i] = make_float4(px, py, pz, fmaf(px, px, fmaf(py, py, pz * pz)));
    }
}

// ---------------------------------------------------------------------------
// KB: scatter known points into cell table (fixed 32 slots; overflow -> cnt>32)
// ---------------------------------------------------------------------------
__global__ __launch_bounds__(256) void bin_scatter_kernel(
    const float* __restrict__ kxyz, float4* __restrict__ table,
    int* __restrict__ cnt)
{
    int i = blockIdx.x * 256 + threadIdx.x;
    if (i >= BB * SS) return;
    int b = i >> 11, s = i & 2047;
    const float* p = kxyz + (size_t)i * 3;
    float x = p[0], y = p[1], z = p[2];
    int cx = min((int)(x * GDIM), GDIM - 1);
    int cy = min((int)(y * GDIM), GDIM - 1);
    int cz = min((int)(z * GDIM), GDIM - 1);
    int cell = (cz * GDIM + cy) * GDIM + cx;
    int slot = atomicAdd(&cnt[b * NCELL + cell], 1);
    if (slot < SLOTS)
        table[((size_t)(b * NCELL + cell)) * SLOTS + slot] =
            make_float4(x, y, z, __int_as_float(s));
}

// ---------------------------------------------------------------------------
// KG: grid 3-NN. 4 threads/query, 2 cells (64 slots) each; quad shfl merge;
// lane (t&3)==0 rescues, writes widx, fail-checks.
// ---------------------------------------------------------------------------
__global__ __launch_bounds__(256) void nn_grid_kernel(
    const float* __restrict__ uxyz, const float4* __restrict__ table,
    const int* __restrict__ cnt, const float4* __restrict__ kpack,
    uint4* __restrict__ widx, int* __restrict__ fail_list,
    int* __restrict__ nfail)
{
    const int t  = blockIdx.x * 256 + threadIdx.x;
    const int qd = t & 3;
    const size_t pt = (size_t)(t >> 2);
    const int b = (int)(pt >> 13);

    const float* up = uxyz + pt * 3;
    const float qx = up[0], qy = up[1], qz = up[2];

    const int cx = min((int)(qx * GDIM), GDIM - 1);
    const int cy = min((int)(qy * GDIM), GDIM - 1);
    const int cz = min((int)(qz * GDIM), GDIM - 1);
    const float fx = qx * GDIM - cx, fy = qy * GDIM - cy, fz = qz * GDIM - cz;
    int ox = cx - (fx <= 0.5f ? 1 : 0); ox = max(0, min(ox, GDIM - 2));
    int oy = cy - (fy <= 0.5f ? 1 : 0); oy = max(0, min(oy, GDIM - 2));
    int oz = cz - (fz <= 0.5f ? 1 : 0); oz = max(0, min(oz, GDIM - 2));

    const float4* tb = table + (size_t)b * NCELL * SLOTS;
    const int* cb = cnt + b * NCELL;

    unsigned int k[5] = {0xFFFFFFFFu, 0xFFFFFFFFu, 0xFFFFFFFFu,
                         0xFFFFFFFFu, 0xFFFFFFFFu};
    int ovf = 0;
#pragma unroll
    for (int jj = 0; jj < 2; ++jj) {
        const int j = qd * 2 + jj;
        const int dx = j & 1, dy = (j >> 1) & 1, dz = j >> 2;
        const int cell = ((oz + dz) * GDIM + (oy + dy)) * GDIM + (ox + dx);
        ovf |= (cb[cell] > SLOTS) ? 1 : 0;
        const float4* cp = tb + (size_t)cell * SLOTS;
#pragma unroll 8
        for (int s = 0; s < SLOTS; ++s) {
            float4 c = cp[s];
            float ddx = c.x - qx, ddy = c.y - qy, ddz = c.z - qz;
            float d = fmaf(ddx, ddx, fmaf(ddy, ddy, ddz * ddz));
            unsigned int key = (__float_as_uint(d) & KEY_MASK) |
                               (unsigned int)__float_as_int(c.w);
            ins5(k, key);
        }
    }

    // quad merge (lanes 4q..4q+3)
#pragma unroll
    for (int m = 1; m <= 2; m <<= 1) {
        unsigned int f0 = (unsigned int)__shfl_xor((int)k[0], m);
        unsigned int f1 = (unsigned int)__shfl_xor((int)k[1], m);
        unsigned int f2 = (unsigned int)__shfl_xor((int)k[2], m);
        unsigned int f3 = (unsigned int)__shfl_xor((int)k[3], m);
        unsigned int f4 = (unsigned int)__shfl_xor((int)k[4], m);
        ovf |= __shfl_xor(ovf, m);
        ins5(k, f0); ins5(k, f1); ins5(k, f2); ins5(k, f3); ins5(k, f4);
    }

    if (qd != 0) return;

    float d3 = rescue_write(k, qx, qy, qz, kpack + (size_t)b * SS, widx, pt);

    // guarantee radius (domain edges fully covered)
    float lx = ox * CELLW, rx = (ox + 2) * CELLW;
    float ly = oy * CELLW, ry = (oy + 2) * CELLW;
    float lz = oz * CELLW, rz = (oz + 2) * CELLW;
    float covx = fminf(ox == 0 ? 1e30f : qx - lx, ox == GDIM - 2 ? 1e30f : rx - qx);
    float covy = fminf(oy == 0 ? 1e30f : qy - ly, oy == GDIM - 2 ? 1e30f : ry - qy);
    float covz = fminf(oz == 0 ? 1e30f : qz - lz, oz == GDIM - 2 ? 1e30f : rz - qz);
    float g = fminf(covx, fminf(covy, covz));

    if (ovf || !(d3 <= g * g)) {
        int pos = atomicAdd(nfail, 1);
        fail_list[pos] = (int)pt;
    }
}

// ---------------------------------------------------------------------------
// KF: brute-force fallback. One wave per failed query; 64 lanes x 32 pts,
// shuffle-tree merge, lane 0 rescues + writes widx.
// ---------------------------------------------------------------------------
__global__ __launch_bounds__(256) void nn_brute_kernel(
    const float* __restrict__ uxyz, const float4* __restrict__ kpack,
    const int* __restrict__ fail_list, const int* __restrict__ nfail,
    uint4* __restrict__ widx)
{
    const int l = threadIdx.x & 63;
    const int wv = (blockIdx.x * 256 + threadIdx.x) >> 6;
    const int nw = (gridDim.x * 256) >> 6;
    const int n = *nfail;

    for (int q = wv; q < n; q += nw) {
        const size_t pt = (size_t)fail_list[q];
        const int b = (int)(pt >> 13);
        const float* up = uxyz + pt * 3;
        const float qx = up[0], qy = up[1], qz = up[2];
        const float4* kp = kpack + (size_t)b * SS;

        unsigned int k[5] = {0xFFFFFFFFu, 0xFFFFFFFFu, 0xFFFFFFFFu,
                             0xFFFFFFFFu, 0xFFFFFFFFu};
#pragma unroll 4
        for (int s = l; s < SS; s += 64) {
            float4 c = kp[s];
            float ddx = c.x - qx, ddy = c.y - qy, ddz = c.z - qz;
            float d = fmaf(ddx, ddx, fmaf(ddy, ddy, ddz * ddz));
            unsigned int key = (__float_as_uint(d) & KEY_MASK) | (unsigned int)s;
            ins5(k, key);
        }
#pragma unroll
        for (int m = 1; m <= 32; m <<= 1) {
            unsigned int f0 = (unsigned int)__shfl_xor((int)k[0], m);
            unsigned int f1 = (unsigned int)__shfl_xor((int)k[1], m);
            unsigned int f2 = (unsigned int)__shfl_xor((int)k[2], m);
            unsigned int f3 = (unsigned int)__shfl_xor((int)k[3], m);
            unsigned int f4 = (unsigned int)__shfl_xor((int)k[4], m);
            ins5(k, f0); ins5(k, f1); ins5(k, f2); ins5(k, f3); ins5(k, f4);
        }
        if (l == 0)
            rescue_write(k, qx, qy, qz, kp, widx, pt);
    }
}

// ---------------------------------------------------------------------------
// KZ: Z = bf16(kpts) @ Wb^T.  (proven R4-R8)
// ---------------------------------------------------------------------------
__global__ __launch_bounds__(512, 4) void zgemm_kernel(
    const float* __restrict__ kpts,
    const unsigned short* __restrict__ Wb,
    unsigned short* __restrict__ Z)
{
    __shared__ __align__(128) unsigned char smem[2 * 32768];

    const int tid = threadIdx.x;
    const int l = tid & 63, w = tid >> 6;
    const int wm = w >> 2, wn = w & 3;
    const int mt = blockIdx.x >> 1, nh = blockIdx.x & 1;
    const int row0 = mt * 128;
    const int srow = l >> 3, sbo = (l & 7) * 16;
    const int lr = tid >> 2, lcq = tid & 3;

    f32x4 acc[4][2];
#pragma unroll
    for (int m = 0; m < 4; ++m)
#pragma unroll
        for (int n = 0; n < 2; ++n) {
            f32x4 z = {0.f, 0.f, 0.f, 0.f};
            acc[m][n] = z;
        }

    const unsigned char* Bb = (const unsigned char*)Wb + (size_t)nh * 128 * 512;
    float4 af0, af1, af2, af3;

    auto issueA = [&](int t) {
        const float* src = kpts + (size_t)(row0 + lr) * 256 + t * 64 + lcq * 16;
        af0 = ((const float4*)src)[0];
        af1 = ((const float4*)src)[1];
        af2 = ((const float4*)src)[2];
        af3 = ((const float4*)src)[3];
    };
    auto stageB = [&](int buf, int t) {
        unsigned char* Bl = smem + buf * 32768 + 16384;
#pragma unroll
        for (int i = 0; i < 2; ++i) {
            const int r = w * 16 + i * 8 + srow;
            gload_lds16(Bb + (size_t)r * 512 + t * 128 + (sbo ^ ((r & 7) << 4)),
                        Bl + r * 128 + sbo);
        }
    };
    auto xformA = [&](int buf) {
        unsigned char* Al = smem + buf * 32768;
        short8 o0, o1;
        o0[0] = (short)f2bf(af0.x); o0[1] = (short)f2bf(af0.y);
        o0[2] = (short)f2bf(af0.z); o0[3] = (short)f2bf(af0.w);
        o0[4] = (short)f2bf(af1.x); o0[5] = (short)f2bf(af1.y);
        o0[6] = (short)f2bf(af1.z); o0[7] = (short)f2bf(af1.w);
        o1[0] = (short)f2bf(af2.x); o1[1] = (short)f2bf(af2.y);
        o1[2] = (short)f2bf(af2.z); o1[3] = (short)f2bf(af2.w);
        o1[4] = (short)f2bf(af3.x); o1[5] = (short)f2bf(af3.y);
        o1[6] = (short)f2bf(af3.z); o1[7] = (short)f2bf(af3.w);
        const int bo = lcq * 32;
        *(short8*)(Al + lr * 128 + ((bo) ^ ((lr & 7) << 4))) = o0;
        *(short8*)(Al + lr * 128 + ((bo + 16) ^ ((lr & 7) << 4))) = o1;
    };
    auto compute = [&](int buf) {
        const unsigned char* Al = smem + buf * 32768;
        const unsigned char* Bl = Al + 16384;
#pragma unroll
        for (int ks = 0; ks < 2; ++ks) {
            const int bo = ks * 64 + (l >> 4) * 16;
            short8 a[4], bq[2];
#pragma unroll
            for (int m = 0; m < 4; ++m) {
                const int r = wm * 64 + m * 16 + (l & 15);
                a[m] = *(const short8*)(Al + r * 128 + (bo ^ ((r & 7) << 4)));
            }
#pragma unroll
            for (int n = 0; n < 2; ++n) {
                const int r = wn * 32 + n * 16 + (l & 15);
                bq[n] = *(const short8*)(Bl + r * 128 + (bo ^ ((r & 7) << 4)));
            }
#pragma unroll
            for (int m = 0; m < 4; ++m)
#pragma unroll
                for (int n = 0; n < 2; ++n)
                    acc[m][n] = __builtin_amdgcn_mfma_f32_16x16x32_bf16(
                        a[m], bq[n], acc[m][n], 0, 0, 0);
        }
    };

    issueA(0);
    stageB(0, 0);
    xformA(0);
    __syncthreads();
#pragma unroll
    for (int t = 0; t < 4; ++t) {
        const int cur = t & 1;
        if (t + 1 < 4) { issueA(t + 1); stageB(cur ^ 1, t + 1); }
        compute(cur);
        if (t + 1 < 4) xformA(cur ^ 1);
        __syncthreads();
    }

#pragma unroll
    for (int m = 0; m < 4; ++m) {
        const int row = row0 + wm * 64 + m * 16 + (l >> 4) * 4;
#pragma unroll
        for (int n = 0; n < 2; ++n) {
            const int col = nh * 128 + wn * 32 + n * 16 + (l & 15);
            f32x4 v = acc[m][n];
#pragma unroll
            for (int r = 0; r < 4; ++r)
                Z[(size_t)(row + r) * 256 + col] = f2bf(v[r]);
        }
    }
}

// ---------------------------------------------------------------------------
// KI: interp from widx: gather 3 Z rows (512B bf16, L2-hot) -> xz bf16.
// ---------------------------------------------------------------------------
__global__ __launch_bounds__(256) void interp_z_kernel(
    const uint4* __restrict__ widx,
    const unsigned short* __restrict__ Z,
    unsigned short* __restrict__ xz)
{
    __shared__ int   sidx[64][3];
    __shared__ float sw[64][3];

    const int tid = threadIdx.x;
    const int bid = blockIdx.x;
    const int b   = bid & 7;
    const int pn  = (bid >> 3) * 64;

    if (tid < 64) {
        uint4 wv = widx[(size_t)b * NN + pn + tid];
        float w0 = __uint_as_float(wv.x);
        float w1 = __uint_as_float(wv.y);
        sidx[tid][0] = (int)(wv.z & 0xFFFFu);
        sidx[tid][1] = (int)(wv.z >> 16);
        sidx[tid][2] = (int)wv.w;
        sw[tid][0] = w0; sw[tid][1] = w1; sw[tid][2] = 1.0f - w0 - w1;
    }
    __syncthreads();

    const int wvv = tid >> 6, lane = tid & 63;
    const unsigned short* Zb = Z + (size_t)b * SS * 256;
    for (int p = wvv; p < 64; p += 4) {
        const int j0 = sidx[p][0], j1 = sidx[p][1], j2 = sidx[p][2];
        const float w0 = sw[p][0], w1 = sw[p][1], w2 = sw[p][2];

        ushort4 z0 = *(const ushort4*)(Zb + (size_t)j0 * 256 + lane * 4);
        ushort4 z1 = *(const ushort4*)(Zb + (size_t)j1 * 256 + lane * 4);
        ushort4 z2 = *(const ushort4*)(Zb + (size_t)j2 * 256 + lane * 4);
        ushort4 o;
        o.x = f2bf(fmaf(w2, bf2f(z2.x), fmaf(w1, bf2f(z1.x), w0 * bf2f(z0.x))));
        o.y = f2bf(fmaf(w2, bf2f(z2.y), fmaf(w1, bf2f(z1.y), w0 * bf2f(z0.y))));
        o.z = f2bf(fmaf(w2, bf2f(z2.z), fmaf(w1, bf2f(z1.z), w0 * bf2f(z0.z))));
        o.w = f2bf(fmaf(w2, bf2f(z2.w), fmaf(w1, bf2f(z1.w), w0 * bf2f(z0.w))));
        *(ushort4*)(xz + ((size_t)b * NN + pn + p) * 256 + lane * 4) = o;
    }
}

// ---------------------------------------------------------------------------
// K1c: gemm1z  y0 = upts@Wa^T + xz; stats0.  (proven R6-R8)
// ---------------------------------------------------------------------------
__global__ __launch_bounds__(512, 4) void gemm1z_kernel(
    const float* __restrict__ upts,
    const unsigned short* __restrict__ Wa,
    const unsigned short* __restrict__ xz,
    unsigned short* __restrict__ Y0,
    float* __restrict__ stats)
{
    __shared__ __align__(128) unsigned char smem[65536];

    const int tid = threadIdx.x;
    const int l = tid & 63, w = tid >> 6;
    const int wm = w >> 2, wn = w & 3;
    const int mt = blockIdx.x >> 1, nh = blockIdx.x & 1;
    const int row0 = mt * 128;
    const int srow = l >> 3, sbo = (l & 7) * 16;
    const int lr = tid >> 2, lcq = tid & 3;

    {
        const unsigned char* Bb = (const unsigned char*)Wa + (size_t)nh * 128 * 256;
#pragma unroll
        for (int h = 0; h < 2; ++h)
#pragma unroll
            for (int i = 0; i < 2; ++i) {
                const int r = w * 16 + i * 8 + srow;
                gload_lds16(Bb + (size_t)r * 256 + h * 128 + (sbo ^ ((r & 7) << 4)),
                            smem + 32768 + h * 16384 + r * 128 + sbo);
            }
    }
    {
        const float* src = upts + (size_t)(row0 + lr) * 128 + lcq * 32;
        float4 f[8];
#pragma unroll
        for (int q = 0; q < 8; ++q) f[q] = ((const float4*)src)[q];
        unsigned char* Ah = smem + (lcq >> 1) * 16384;
        const int cb = (lcq & 1) * 64;
#pragma unroll
        for (int q = 0; q < 4; ++q) {
            float4 fa = f[q * 2], fb = f[q * 2 + 1];
            short8 o;
            o[0] = (short)f2bf(fa.x); o[1] = (short)f2bf(fa.y);
            o[2] = (short)f2bf(fa.z); o[3] = (short)f2bf(fa.w);
            o[4] = (short)f2bf(fb.x); o[5] = (short)f2bf(fb.y);
            o[6] = (short)f2bf(fb.z); o[7] = (short)f2bf(fb.w);
            *(short8*)(Ah + lr * 128 + ((cb + q * 16) ^ ((lr & 7) << 4))) = o;
        }
    }
    __syncthreads();

    f32x4 acc[4][2];
#pragma unroll
    for (int m = 0; m < 4; ++m)
#pragma unroll
        for (int n = 0; n < 2; ++n) {
            f32x4 z = {0.f, 0.f, 0.f, 0.f};
            acc[m][n] = z;
        }
#pragma unroll
    for (int ks = 0; ks < 4; ++ks) {
        const unsigned char* Al = smem + (ks >> 1) * 16384;
        const unsigned char* Bl = smem + 32768 + (ks >> 1) * 16384;
        const int bo = (ks & 1) * 64 + (l >> 4) * 16;
        short8 a[4], bq[2];
#pragma unroll
        for (int m = 0; m < 4; ++m) {
            const int r = wm * 64 + m * 16 + (l & 15);
            a[m] = *(const short8*)(Al + r * 128 + (bo ^ ((r & 7) << 4)));
        }
#pragma unroll
        for (int n = 0; n < 2; ++n) {
            const int r = wn * 32 + n * 16 + (l & 15);
            bq[n] = *(const short8*)(Bl + r * 128 + (bo ^ ((r & 7) << 4)));
        }
#pragma unroll
        for (int m = 0; m < 4; ++m)
#pragma unroll
            for (int n = 0; n < 2; ++n)
                acc[m][n] = __builtin_amdgcn_mfma_f32_16x16x32_bf16(
                    a[m], bq[n], acc[m][n], 0, 0, 0);
    }

    float s1[2] = {0.f, 0.f}, s2[2] = {0.f, 0.f};
#pragma unroll
    for (int m = 0; m < 4; ++m) {
#pragma unroll
        for (int r = 0; r < 4; ++r) {
            const int row = row0 + wm * 64 + m * 16 + (l >> 4) * 4 + r;
#pragma unroll
            for (int n = 0; n < 2; ++n) {
                const int col = nh * 128 + wn * 32 + n * 16 + (l & 15);
                float f = acc[m][n][r] + bf2f(xz[(size_t)row * 256 + col]);
                Y0[(size_t)row * 256 + col] = f2bf(f);
                s1[n] += f;
                s2[n] += f * f;
            }
        }
    }
#pragma unroll
    for (int n = 0; n < 2; ++n) {
        s1[n] += __shfl_xor(s1[n], 16, 64);
        s1[n] += __shfl_xor(s1[n], 32, 64);
        s2[n] += __shfl_xor(s2[n], 16, 64);
        s2[n] += __shfl_xor(s2[n], 32, 64);
    }
    if (l < 16) {
#pragma unroll
        for (int n = 0; n < 2; ++n) {
            const int col = nh * 128 + wn * 32 + n * 16 + l;
            atomicAdd(&stats[col], s1[n]);
            atomicAdd(&stats[N1DIM + col], s2[n]);
        }
    }
}

// ---------------------------------------------------------------------------
// K4: GEMM2  y1 = relu(bn0(y0)) @ W1^T  (proven; Y1 bf16)
// ---------------------------------------------------------------------------
#define G2_NT (K2DIM / BK)   // 4
__global__ __launch_bounds__(512, 4) void gemm2_kernel(
    const unsigned short* __restrict__ Y0,
    const unsigned short* __restrict__ Wb,
    const float* __restrict__ stats0,
    const float* __restrict__ g0,
    const float* __restrict__ beta0,
    unsigned short* __restrict__ Y1,
    float* __restrict__ stats)
{
    __shared__ __align__(128) unsigned char smem[2 * 32768];
    __shared__ float sgm[K2DIM], sga[K2DIM];

    const int tid = threadIdx.x;
    const int l = tid & 63, w = tid >> 6;
    const int wm = w >> 2, wn = w & 3;
    const int row0 = blockIdx.x * 128;
    const int srow = l >> 3;
    const int sbo  = (l & 7) * 16;
    const int lr  = tid >> 2;
    const int lcq = tid & 3;

    f32x4 acc[4][2];
#pragma unroll
    for (int m = 0; m < 4; ++m)
#pragma unroll
        for (int n = 0; n < 2; ++n) {
            f32x4 z = {0.f, 0.f, 0.f, 0.f};
            acc[m][n] = z;
        }

    const unsigned char* Bb = (const unsigned char*)Wb;
    short8 areg0, areg1;

    auto issueA = [&](int t) {
        const unsigned short* src = Y0 + (size_t)(row0 + lr) * K2DIM + t * BK + lcq * 16;
        areg0 = *(const short8*)src;
        areg1 = *(const short8*)(src + 8);
    };
    auto stageB = [&](int buf, int t) {
        unsigned char* Bl = smem + buf * 32768 + 16384;
        const int k0b = t * (BK * 2);
#pragma unroll
        for (int i = 0; i < 2; ++i) {
            const int r = w * 16 + i * 8 + srow;
            gload_lds16(Bb + (size_t)r * (K2DIM * 2) + k0b + (sbo ^ ((r & 7) << 4)),
                        Bl + r * 128 + sbo);
        }
    };
    auto xformA = [&](int buf, int t) {
        unsigned char* Al = smem + buf * 32768;
        const int kb = t * BK + lcq * 16;
        short8 o0, o1;
#pragma unroll
        for (int j = 0; j < 8; ++j) {
            float f = bf2f((unsigned short)areg0[j]);
            f = fmaxf(fmaf(f, sgm[kb + j], sga[kb + j]), 0.f);
            o0[j] = (short)f2bf(f);
            float g = bf2f((unsigned short)areg1[j]);
            g = fmaxf(fmaf(g, sgm[kb + 8 + j], sga[kb + 8 + j]), 0.f);
            o1[j] = (short)f2bf(g);
        }
        const int bo = lcq * 32;
        *(short8*)(Al + lr * 128 + ((bo) ^ ((lr & 7) << 4))) = o0;
        *(short8*)(Al + lr * 128 + ((bo + 16) ^ ((lr & 7) << 4))) = o1;
    };
    auto compute = [&](int buf) {
        const unsigned char* Al = smem + buf * 32768;
        const unsigned char* Bl = Al + 16384;
#pragma unroll
        for (int ks = 0; ks < 2; ++ks) {
            const int bo = ks * 64 + (l >> 4) * 16;
            short8 a[4], bq[2];
#pragma unroll
            for (int m = 0; m < 4; ++m) {
                const int r = wm * 64 + m * 16 + (l & 15);
                a[m] = *(const short8*)(Al + r * 128 + (bo ^ ((r & 7) << 4)));
            }
#pragma unroll
            for (int n = 0; n < 2; ++n) {
                const int r = wn * 32 + n * 16 + (l & 15);
                bq[n] = *(const short8*)(Bl + r * 128 + (bo ^ ((r & 7) << 4)));
            }
#pragma unroll
            for (int m = 0; m < 4; ++m)
#pragma unroll
                for (int n = 0; n < 2; ++n)
                    acc[m][n] = __builtin_amdgcn_mfma_f32_16x16x32_bf16(
                        a[m], bq[n], acc[m][n], 0, 0, 0);
        }
    };

    if (tid < K2DIM) {
        const float inv = 1.0f / (float)M_TOT;
        float mean = stats0[tid] * inv;
        float var  = stats0[N1DIM + tid] * inv - mean * mean;
        float m = g0[tid] * rsqrtf(var + 1e-5f);
        sgm[tid] = m;
        sga[tid] = beta0[tid] - mean * m;
    }
    issueA(0);
    stageB(0, 0);
    __syncthreads();
    xformA(0, 0);
    __syncthreads();

#pragma unroll
    for (int t = 0; t < G2_NT; ++t) {
        const int cur = t & 1;
        if (t + 1 < G2_NT) { issueA(t + 1); stageB(cur ^ 1, t + 1); }
        compute(cur);
        if (t + 1 < G2_NT) xformA(cur ^ 1, t + 1);
        __syncthreads();
    }

    float s1[2] = {0.f, 0.f}, s2[2] = {0.f, 0.f};
#pragma unroll
    for (int m = 0; m < 4; ++m) {
        const int row = row0 + wm * 64 + m * 16 + (l >> 4) * 4;
#pragma unroll
        for (int n = 0; n < 2; ++n) {
            const int col = wn * 32 + n * 16 + (l & 15);
            f32x4 v = acc[m][n];
#pragma unroll
            for (int r = 0; r < 4; ++r) {
                float f = v[r];
                Y1[(size_t)(row + r) * N2DIM + col] = f2bf(f);
                s1[n] += f;
                s2[n] += f * f;
            }
        }
    }
#pragma unroll
    for (int n = 0; n < 2; ++n) {
        s1[n] += __shfl_xor(s1[n], 16, 64);
        s1[n] += __shfl_xor(s1[n], 32, 64);
        s2[n] += __shfl_xor(s2[n], 16, 64);
        s2[n] += __shfl_xor(s2[n], 32, 64);
    }
    if (l < 16) {
#pragma unroll
        for (int n = 0; n < 2; ++n) {
            const int col = wn * 32 + n * 16 + l;
            atomicAdd(&stats[col], s1[n]);
            atomicAdd(&stats[N2DIM + col], s2[n]);
        }
    }
}

// ---------------------------------------------------------------------------
// K6: out = relu(bn1(y1)), BN1 finalize inlined; y1 bf16 in, out f32.
// ---------------------------------------------------------------------------
__global__ __launch_bounds__(256) void bn_out_kernel(
    const unsigned short* __restrict__ Y1, const float* __restrict__ stats1,
    const float* __restrict__ g1, const float* __restrict__ beta1,
    float* __restrict__ out)
{
    __shared__ float sgm[N2DIM], sga[N2DIM];
    const int tid = threadIdx.x;
    if (tid < N2DIM) {
        const float inv = 1.0f / (float)M_TOT;
        float mean = stats1[tid] * inv;
        float var  = stats1[N2DIM + tid] * inv - mean * mean;
        float m = g1[tid] * rsqrtf(var + 1e-5f);
        sgm[tid] = m;
        sga[tid] = beta1[tid] - mean * m;
    }
    __syncthreads();

    const int total = M_TOT * N2DIM / 8;
    for (int i = blockIdx.x * 256 + tid; i < total; i += gridDim.x * 256) {
        short8 v = ((const short8*)Y1)[i];
        const int cg = (i & 15) * 8;
        float4 o1, o2;
        o1.x = fmaxf(fmaf(bf2f((unsigned short)v[0]), sgm[cg + 0], sga[cg + 0]), 0.f);
        o1.y = fmaxf(fmaf(bf2f((unsigned short)v[1]), sgm[cg + 1], sga[cg + 1]), 0.f);
        o1.z = fmaxf(fmaf(bf2f((unsigned short)v[2]), sgm[cg + 2], sga[cg + 2]), 0.f);
        o1.w = fmaxf(fmaf(bf2f((unsigned short)v[3]), sgm[cg + 3], sga[cg + 3]), 0.f);
        o2.x = fmaxf(fmaf(bf2f((unsigned short)v[4]), sgm[cg + 4], sga[cg + 4]), 0.f);
        o2.y = fmaxf(fmaf(bf2f((unsigned short)v[5]), sgm[cg + 5], sga[cg + 5]), 0.f);
        o2.z = fmaxf(fmaf(bf2f((unsigned short)v[6]), sgm[cg + 6], sga[cg + 6]), 0.f);
        o2.w = fmaxf(fmaf(bf2f((unsigned short)v[7]), sgm[cg + 7], sga[cg + 7]), 0.f);
        ((float4*)out)[i * 2]     = o1;
        ((float4*)out)[i * 2 + 1] = o2;
    }
}

// ---------------------------------------------------------------------------
// launch
// ---------------------------------------------------------------------------
extern "C" void kernel_launch(void* const* d_in, const int* in_sizes, int n_in,
                              void* d_out, int out_size, void* d_ws, size_t ws_size,
                              hipStream_t stream)
{
    const float* uxyz  = (const float*)d_in[0];
    const float* kxyz  = (const float*)d_in[1];
    const float* upts  = (const float*)d_in[2];
    const float* kpts  = (const float*)d_in[3];
    const float* W0    = (const float*)d_in[4];
    const float* g0    = (const float*)d_in[6];
    const float* beta0 = (const float*)d_in[7];
    const float* W1    = (const float*)d_in[8];
    const float* g1    = (const float*)d_in[10];
    const float* beta1 = (const float*)d_in[11];
    float* out = (float*)d_out;

    char* ws = (char*)d_ws;
    const size_t off_xz = 0;                 // xz bf16 [M][256] 33.5MB; y1 bf16 aliases
    const size_t off_y0 = 33554432;          // y0 bf16 [M][256]; grid structs + kpack alias
    const size_t off_z  = 67108864;          // Z bf16 [16384][256] 8.4MB
    const size_t off_w  = 75497472;          // weights + stats + widx

    unsigned short* xz   = (unsigned short*)(ws + off_xz);
    unsigned short* y1   = (unsigned short*)(ws + off_xz);        // aliases xz
    unsigned short* y0   = (unsigned short*)(ws + off_y0);
    // grid structs alias the y0 region (consumed before gemm1z writes y0)
    float4* table    = (float4*)(ws + off_y0);                    // 512KB
    int*    cellcnt  = (int*)(ws + off_y0 + 524288);              // 4KB
    int*    nfail    = (int*)(ws + off_y0 + 528384);              // 4B
    int*    faillist = (int*)(ws + off_y0 + 532480);              // 256KB
    float4* kpack    = (float4*)(ws + off_y0 + 8388608);          // 256KB
    unsigned short* Zb   = (unsigned short*)(ws + off_z);
    unsigned short* wa   = (unsigned short*)(ws + off_w);
    unsigned short* wb   = (unsigned short*)(ws + off_w + 65536);
    unsigned short* wb1  = (unsigned short*)(ws + off_w + 196608);
    float* F = (float*)(ws + off_w + 262144);
    float* stats0 = F;           // [512]
    float* stats1 = F + 512;     // [256]
    uint4* widx = (uint4*)(ws + off_w + 270336);                  // 1MB

    cvt_w_kernel<<<384, 256, 0, stream>>>(W0, W1, kxyz, wa, wb, wb1, kpack,
                                          table, cellcnt, nfail, F);
    bin_scatter_kernel<<<64, 256, 0, stream>>>(kxyz, table, cellcnt);
    nn_grid_kernel<<<1024, 256, 0, stream>>>(uxyz, table, cellcnt, kpack,
                                             widx, faillist, nfail);
    nn_brute_kernel<<<256, 256, 0, stream>>>(uxyz, kpack, faillist, nfail, widx);
    zgemm_kernel<<<256, 512, 0, stream>>>(kpts, wb, Zb);
    interp_z_kernel<<<1024, 256, 0, stream>>>(widx, Zb, xz);
    gemm1z_kernel<<<1024, 512, 0, stream>>>(upts, wa, xz, y0, stats0);
    gemm2_kernel<<<512, 512, 0, stream>>>(y0, wb1, stats0, g0, beta0, y1, stats1);
    bn_out_kernel<<<2048, 256, 0, stream>>>(y1, stats1, g1, beta1, out);
}

// Round 10
// 151.501 us; speedup vs baseline: 1.0747x; 1.0747x over previous
//
#include <hip/hip_runtime.h>
#include <hip/hip_bf16.h>

// ---------------------------------------------------------------------------
// PointNet Feature Propagation, MI355X (gfx950)
//   Algebra: y0 = upts@W0a^T + sum_j w_j * Z[idx_j],  Z = kpts@W0b^T
//   3-NN via 5^3 spatial grid (exact: top-5 + rescue + brute fail path).
//   KB:  bin_scatter  known pts -> [B][125][32] cell table
//   KG:  nn_grid      4 thr/query, 2x2x2 block -> top5 -> rescue -> widx
//   KF:  nn_brute     1 wave/failed query
//   KZ:  zgemm        Z = bf16(kpts) @ W0b^T
//   K1u: gemm1u       Y0u = upts@Wa^T (LDS-transposed, coalesced bf16 write)
//   KI:  interp_y0    y0 = Y0u + interp(Z) (all-streaming) + stats0 (8-replica)
//   K4:  gemm2 (BN0 finalize from replicas, BN0+ReLU fused A) -> y1 bf16
//   K6:  bn_out (BN1 finalize inline) -> out f32
// ---------------------------------------------------------------------------

typedef __attribute__((ext_vector_type(8))) short short8;
typedef __attribute__((ext_vector_type(4))) float f32x4;

#define BB 8
#define NN 8192
#define SS 2048
#define M_TOT (BB * NN)      // 65536 points
#define N1DIM 256
#define K2DIM 256
#define N2DIM 128
#define BK 64

#define GDIM 5
#define NCELL (GDIM * GDIM * GDIM)   // 125
#define SLOTS 32
#define CELLW 0.2f

#define KEY_MASK 0xFFFFF800u
#define IDX_MASK 0x7FFu

__device__ __forceinline__ unsigned short f2bf(float f) {
    unsigned int x = __float_as_uint(f);
    unsigned int r = x + 0x7fffu + ((x >> 16) & 1u);  // RNE
    return (unsigned short)(r >> 16);
}
__device__ __forceinline__ float bf2f(unsigned short u) {
    return __uint_as_float(((unsigned int)u) << 16);
}
__device__ __forceinline__ unsigned int med3_u32(unsigned int a, unsigned int b,
                                                 unsigned int c) {
    unsigned int r;
    asm("v_med3_u32 %0, %1, %2, %3" : "=v"(r) : "v"(a), "v"(b), "v"(c));
    return r;
}

// insert key into sorted ascending k[0..4]
__device__ __forceinline__ void ins5(unsigned int k[5], unsigned int key) {
    unsigned int n1 = med3_u32(k[0], k[1], key);
    unsigned int n2 = med3_u32(k[1], k[2], key);
    unsigned int n3 = med3_u32(k[2], k[3], key);
    unsigned int n4 = med3_u32(k[3], k[4], key);
    k[0] = min(k[0], key);
    k[1] = n1; k[2] = n2; k[3] = n3; k[4] = n4;
}

// exact-distance rescue of quantized top-5 -> widx write; returns exact d3.
__device__ __forceinline__ float rescue_write(
    const unsigned int k[5], float qx, float qy, float qz,
    const float4* __restrict__ kpB, uint4* __restrict__ widx, size_t pt)
{
    unsigned long long e[5];
#pragma unroll
    for (int i = 0; i < 5; ++i) {
        if ((k[i] & KEY_MASK) >= 0x7F800000u) {
            e[i] = 0xFFFFFFFFFFFFFFFFull;
        } else {
            unsigned int idx = k[i] & IDX_MASK;
            float4 c = kpB[idx];
            float dx = c.x - qx, dy = c.y - qy, dz = c.z - qz;
            float d = fmaf(dx, dx, fmaf(dy, dy, dz * dz));
            e[i] = ((unsigned long long)__float_as_uint(d) << 32) | idx;
        }
    }
#pragma unroll
    for (int i = 0; i < 3; ++i)
#pragma unroll
        for (int j = i + 1; j < 5; ++j)
            if (e[j] < e[i]) { unsigned long long t = e[i]; e[i] = e[j]; e[j] = t; }

    float d0 = __uint_as_float((unsigned int)(e[0] >> 32));
    float d1 = __uint_as_float((unsigned int)(e[1] >> 32));
    float d2 = __uint_as_float((unsigned int)(e[2] >> 32));
    float r0 = 1.0f / (d0 + 1e-8f);
    float r1 = 1.0f / (d1 + 1e-8f);
    float r2 = 1.0f / (d2 + 1e-8f);
    float rs = 1.0f / (r0 + r1 + r2);
    unsigned int i0 = (unsigned int)(e[0] & IDX_MASK);
    unsigned int i1 = (unsigned int)(e[1] & IDX_MASK);
    unsigned int i2 = (unsigned int)(e[2] & IDX_MASK);
    widx[pt] = make_uint4(__float_as_uint(r0 * rs), __float_as_uint(r1 * rs),
                          i0 | (i1 << 16), i2);
    return d2;
}

// async 16B global->LDS DMA (wave-uniform LDS base + lane*16).
__device__ __forceinline__ void gload_lds16(const void* g, void* lds) {
    __builtin_amdgcn_global_load_lds(
        (const __attribute__((address_space(1))) unsigned int*)g,
        (__attribute__((address_space(3))) unsigned int*)lds, 16, 0, 0);
}

// ---------------------------------------------------------------------------
// K0: weights cvt + kpack + grid-table fill + stats zero (4608 floats).
// ---------------------------------------------------------------------------
__global__ __launch_bounds__(256) void cvt_w_kernel(
    const float* __restrict__ W0, const float* __restrict__ W1,
    const float* __restrict__ kxyz,
    unsigned short* __restrict__ Wa, unsigned short* __restrict__ Wb,
    unsigned short* __restrict__ Wb1, float4* __restrict__ kpack,
    float4* __restrict__ table, int* __restrict__ cnt,
    int* __restrict__ nfail, float* __restrict__ statsF)
{
    int i = blockIdx.x * 256 + threadIdx.x;
    if (blockIdx.x == 0) {
        for (int j = threadIdx.x; j < 4608; j += 256) statsF[j] = 0.0f;
        if (threadIdx.x == 0) *nfail = 0;
    }
    if (i < BB * NCELL) cnt[i] = 0;
    if (i < BB * NCELL * SLOTS)
        table[i] = make_float4(1e30f, 1e30f, 1e30f, 0.0f);
    if (i < 256 * 384) {
        int o = i / 384, c = i - o * 384;
        unsigned short v = f2bf(W0[i]);
        if (c < 128) Wa[o * 128 + c] = v;
        else         Wb[o * 256 + (c - 128)] = v;
    }
    if (i < N2DIM * K2DIM) Wb1[i] = f2bf(W1[i]);
    if (i < BB * SS) {
        const float* p = kxyz + (size_t)i * 3;
        float px = p[0], py = p[1], pz = p[2];
        kpack[i] = make_float4(px, py, pz, fmaf(px, px, fmaf(py, py, pz * pz)));
    }
}

// ---------------------------------------------------------------------------
// KB: scatter known points into cell table.
// ---------------------------------------------------------------------------
__global__ __launch_bounds__(256) void bin_scatter_kernel(
    const float* __restrict__ kxyz, float4* __restrict__ table,
    int* __restrict__ cnt)
{
    int i = blockIdx.x * 256 + threadIdx.x;
    if (i >= BB * SS) return;
    int b = i >> 11, s = i & 2047;
    const float* p = kxyz + (size_t)i * 3;
    float x = p[0], y = p[1], z = p[2];
    int cx = min((int)(x * GDIM), GDIM - 1);
    int cy = min((int)(y * GDIM), GDIM - 1);
    int cz = min((int)(z * GDIM), GDIM - 1);
    int cell = (cz * GDIM + cy) * GDIM + cx;
    int slot = atomicAdd(&cnt[b * NCELL + cell], 1);
    if (slot < SLOTS)
        table[((size_t)(b * NCELL + cell)) * SLOTS + slot] =
            make_float4(x, y, z, __int_as_float(s));
}

// ---------------------------------------------------------------------------
// KG: grid 3-NN. 4 threads/query; quad shfl merge; qd==0 rescues + writes.
// ---------------------------------------------------------------------------
__global__ __launch_bounds__(256) void nn_grid_kernel(
    const float* __restrict__ uxyz, const float4* __restrict__ table,
    const int* __restrict__ cnt, const float4* __restrict__ kpack,
    uint4* __restrict__ widx, int* __restrict__ fail_list,
    int* __restrict__ nfail)
{
    const int t  = blockIdx.x * 256 + threadIdx.x;
    const int qd = t & 3;
    const size_t pt = (size_t)(t >> 2);
    const int b = (int)(pt >> 13);

    const float* up = uxyz + pt * 3;
    const float qx = up[0], qy = up[1], qz = up[2];

    const int cx = min((int)(qx * GDIM), GDIM - 1);
    const int cy = min((int)(qy * GDIM), GDIM - 1);
    const int cz = min((int)(qz * GDIM), GDIM - 1);
    const float fx = qx * GDIM - cx, fy = qy * GDIM - cy, fz = qz * GDIM - cz;
    int ox = cx - (fx <= 0.5f ? 1 : 0); ox = max(0, min(ox, GDIM - 2));
    int oy = cy - (fy <= 0.5f ? 1 : 0); oy = max(0, min(oy, GDIM - 2));
    int oz = cz - (fz <= 0.5f ? 1 : 0); oz = max(0, min(oz, GDIM - 2));

    const float4* tb = table + (size_t)b * NCELL * SLOTS;
    const int* cb = cnt + b * NCELL;

    unsigned int k[5] = {0xFFFFFFFFu, 0xFFFFFFFFu, 0xFFFFFFFFu,
                         0xFFFFFFFFu, 0xFFFFFFFFu};
    int ovf = 0;
#pragma unroll
    for (int jj = 0; jj < 2; ++jj) {
        const int j = qd * 2 + jj;
        const int dx = j & 1, dy = (j >> 1) & 1, dz = j >> 2;
        const int cell = ((oz + dz) * GDIM + (oy + dy)) * GDIM + (ox + dx);
        ovf |= (cb[cell] > SLOTS) ? 1 : 0;
        const float4* cp = tb + (size_t)cell * SLOTS;
#pragma unroll 8
        for (int s = 0; s < SLOTS; ++s) {
            float4 c = cp[s];
            float ddx = c.x - qx, ddy = c.y - qy, ddz = c.z - qz;
            float d = fmaf(ddx, ddx, fmaf(ddy, ddy, ddz * ddz));
            unsigned int key = (__float_as_uint(d) & KEY_MASK) |
                               (unsigned int)__float_as_int(c.w);
            ins5(k, key);
        }
    }

#pragma unroll
    for (int m = 1; m <= 2; m <<= 1) {
        unsigned int f0 = (unsigned int)__shfl_xor((int)k[0], m);
        unsigned int f1 = (unsigned int)__shfl_xor((int)k[1], m);
        unsigned int f2 = (unsigned int)__shfl_xor((int)k[2], m);
        unsigned int f3 = (unsigned int)__shfl_xor((int)k[3], m);
        unsigned int f4 = (unsigned int)__shfl_xor((int)k[4], m);
        ovf |= __shfl_xor(ovf, m);
        ins5(k, f0); ins5(k, f1); ins5(k, f2); ins5(k, f3); ins5(k, f4);
    }

    if (qd != 0) return;

    float d3 = rescue_write(k, qx, qy, qz, kpack + (size_t)b * SS, widx, pt);

    float lx = ox * CELLW, rx = (ox + 2) * CELLW;
    float ly = oy * CELLW, ry = (oy + 2) * CELLW;
    float lz = oz * CELLW, rz = (oz + 2) * CELLW;
    float covx = fminf(ox == 0 ? 1e30f : qx - lx, ox == GDIM - 2 ? 1e30f : rx - qx);
    float covy = fminf(oy == 0 ? 1e30f : qy - ly, oy == GDIM - 2 ? 1e30f : ry - qy);
    float covz = fminf(oz == 0 ? 1e30f : qz - lz, oz == GDIM - 2 ? 1e30f : rz - qz);
    float g = fminf(covx, fminf(covy, covz));

    if (ovf || !(d3 <= g * g)) {
        int pos = atomicAdd(nfail, 1);
        fail_list[pos] = (int)pt;
    }
}

// ---------------------------------------------------------------------------
// KF: brute-force fallback, one wave per failed query.
// ---------------------------------------------------------------------------
__global__ __launch_bounds__(256) void nn_brute_kernel(
    const float* __restrict__ uxyz, const float4* __restrict__ kpack,
    const int* __restrict__ fail_list, const int* __restrict__ nfail,
    uint4* __restrict__ widx)
{
    const int l = threadIdx.x & 63;
    const int wv = (blockIdx.x * 256 + threadIdx.x) >> 6;
    const int nw = (gridDim.x * 256) >> 6;
    const int n = *nfail;

    for (int q = wv; q < n; q += nw) {
        const size_t pt = (size_t)fail_list[q];
        const int b = (int)(pt >> 13);
        const float* up = uxyz + pt * 3;
        const float qx = up[0], qy = up[1], qz = up[2];
        const float4* kp = kpack + (size_t)b * SS;

        unsigned int k[5] = {0xFFFFFFFFu, 0xFFFFFFFFu, 0xFFFFFFFFu,
                             0xFFFFFFFFu, 0xFFFFFFFFu};
#pragma unroll 4
        for (int s = l; s < SS; s += 64) {
            float4 c = kp[s];
            float ddx = c.x - qx, ddy = c.y - qy, ddz = c.z - qz;
            float d = fmaf(ddx, ddx, fmaf(ddy, ddy, ddz * ddz));
            unsigned int key = (__float_as_uint(d) & KEY_MASK) | (unsigned int)s;
            ins5(k, key);
        }
#pragma unroll
        for (int m = 1; m <= 32; m <<= 1) {
            unsigned int f0 = (unsigned int)__shfl_xor((int)k[0], m);
            unsigned int f1 = (unsigned int)__shfl_xor((int)k[1], m);
            unsigned int f2 = (unsigned int)__shfl_xor((int)k[2], m);
            unsigned int f3 = (unsigned int)__shfl_xor((int)k[3], m);
            unsigned int f4 = (unsigned int)__shfl_xor((int)k[4], m);
            ins5(k, f0); ins5(k, f1); ins5(k, f2); ins5(k, f3); ins5(k, f4);
        }
        if (l == 0)
            rescue_write(k, qx, qy, qz, kp, widx, pt);
    }
}

// ---------------------------------------------------------------------------
// KZ: Z = bf16(kpts) @ Wb^T.  (proven R4-R9)
// ---------------------------------------------------------------------------
__global__ __launch_bounds__(512, 4) void zgemm_kernel(
    const float* __restrict__ kpts,
    const unsigned short* __restrict__ Wb,
    unsigned short* __restrict__ Z)
{
    __shared__ __align__(128) unsigned char smem[2 * 32768];

    const int tid = threadIdx.x;
    const int l = tid & 63, w = tid >> 6;
    const int wm = w >> 2, wn = w & 3;
    const int mt = blockIdx.x >> 1, nh = blockIdx.x & 1;
    const int row0 = mt * 128;
    const int srow = l >> 3, sbo = (l & 7) * 16;
    const int lr = tid >> 2, lcq = tid & 3;

    f32x4 acc[4][2];
#pragma unroll
    for (int m = 0; m < 4; ++m)
#pragma unroll
        for (int n = 0; n < 2; ++n) {
            f32x4 z = {0.f, 0.f, 0.f, 0.f};
            acc[m][n] = z;
        }

    const unsigned char* Bb = (const unsigned char*)Wb + (size_t)nh * 128 * 512;
    float4 af0, af1, af2, af3;

    auto issueA = [&](int t) {
        const float* src = kpts + (size_t)(row0 + lr) * 256 + t * 64 + lcq * 16;
        af0 = ((const float4*)src)[0];
        af1 = ((const float4*)src)[1];
        af2 = ((const float4*)src)[2];
        af3 = ((const float4*)src)[3];
    };
    auto stageB = [&](int buf, int t) {
        unsigned char* Bl = smem + buf * 32768 + 16384;
#pragma unroll
        for (int i = 0; i < 2; ++i) {
            const int r = w * 16 + i * 8 + srow;
            gload_lds16(Bb + (size_t)r * 512 + t * 128 + (sbo ^ ((r & 7) << 4)),
                        Bl + r * 128 + sbo);
        }
    };
    auto xformA = [&](int buf) {
        unsigned char* Al = smem + buf * 32768;
        short8 o0, o1;
        o0[0] = (short)f2bf(af0.x); o0[1] = (short)f2bf(af0.y);
        o0[2] = (short)f2bf(af0.z); o0[3] = (short)f2bf(af0.w);
        o0[4] = (short)f2bf(af1.x); o0[5] = (short)f2bf(af1.y);
        o0[6] = (short)f2bf(af1.z); o0[7] = (short)f2bf(af1.w);
        o1[0] = (short)f2bf(af2.x); o1[1] = (short)f2bf(af2.y);
        o1[2] = (short)f2bf(af2.z); o1[3] = (short)f2bf(af2.w);
        o1[4] = (short)f2bf(af3.x); o1[5] = (short)f2bf(af3.y);
        o1[6] = (short)f2bf(af3.z); o1[7] = (short)f2bf(af3.w);
        const int bo = lcq * 32;
        *(short8*)(Al + lr * 128 + ((bo) ^ ((lr & 7) << 4))) = o0;
        *(short8*)(Al + lr * 128 + ((bo + 16) ^ ((lr & 7) << 4))) = o1;
    };
    auto compute = [&](int buf) {
        const unsigned char* Al = smem + buf * 32768;
        const unsigned char* Bl = Al + 16384;
#pragma unroll
        for (int ks = 0; ks < 2; ++ks) {
            const int bo = ks * 64 + (l >> 4) * 16;
            short8 a[4], bq[2];
#pragma unroll
            for (int m = 0; m < 4; ++m) {
                const int r = wm * 64 + m * 16 + (l & 15);
                a[m] = *(const short8*)(Al + r * 128 + (bo ^ ((r & 7) << 4)));
            }
#pragma unroll
            for (int n = 0; n < 2; ++n) {
                const int r = wn * 32 + n * 16 + (l & 15);
                bq[n] = *(const short8*)(Bl + r * 128 + (bo ^ ((r & 7) << 4)));
            }
#pragma unroll
            for (int m = 0; m < 4; ++m)
#pragma unroll
                for (int n = 0; n < 2; ++n)
                    acc[m][n] = __builtin_amdgcn_mfma_f32_16x16x32_bf16(
                        a[m], bq[n], acc[m][n], 0, 0, 0);
        }
    };

    issueA(0);
    stageB(0, 0);
    xformA(0);
    __syncthreads();
#pragma unroll
    for (int t = 0; t < 4; ++t) {
        const int cur = t & 1;
        if (t + 1 < 4) { issueA(t + 1); stageB(cur ^ 1, t + 1); }
        compute(cur);
        if (t + 1 < 4) xformA(cur ^ 1);
        __syncthreads();
    }

#pragma unroll
    for (int m = 0; m < 4; ++m) {
        const int row = row0 + wm * 64 + m * 16 + (l >> 4) * 4;
#pragma unroll
        for (int n = 0; n < 2; ++n) {
            const int col = nh * 128 + wn * 32 + n * 16 + (l & 15);
            f32x4 v = acc[m][n];
#pragma unroll
            for (int r = 0; r < 4; ++r)
                Z[(size_t)(row + r) * 256 + col] = f2bf(v[r]);
        }
    }
}

// ---------------------------------------------------------------------------
// K1u: gemm1u  Y0u = upts@Wa^T (bf16).  Epilogue: acc -> LDS [128][136] bf16
// (padded, ~2-4 way max) -> coalesced 64B/thread global write.
// ---------------------------------------------------------------------------
__global__ __launch_bounds__(512, 4) void gemm1u_kernel(
    const float* __restrict__ upts,          // [M][128] f32
    const unsigned short* __restrict__ Wa,   // [256][128] bf16
    unsigned short* __restrict__ Y0u)        // [M][256] bf16
{
    // layout: A0 [0,16K) A1 [16K,32K) B0 [32K,48K) B1 [48K,64K)
    __shared__ __align__(128) unsigned char smem[65536];

    const int tid = threadIdx.x;
    const int l = tid & 63, w = tid >> 6;
    const int wm = w >> 2, wn = w & 3;
    const int mt = blockIdx.x >> 1, nh = blockIdx.x & 1;
    const int row0 = mt * 128;
    const int srow = l >> 3, sbo = (l & 7) * 16;
    const int lr = tid >> 2, lcq = tid & 3;

    // ---- stage B: Wa[nh*128 + r], rows 256B split into 2x128B halves ----
    {
        const unsigned char* Bb = (const unsigned char*)Wa + (size_t)nh * 128 * 256;
#pragma unroll
        for (int h = 0; h < 2; ++h)
#pragma unroll
            for (int i = 0; i < 2; ++i) {
                const int r = w * 16 + i * 8 + srow;
                gload_lds16(Bb + (size_t)r * 256 + h * 128 + (sbo ^ ((r & 7) << 4)),
                            smem + 32768 + h * 16384 + r * 128 + sbo);
            }
    }
    // ---- stage A: upts f32 -> bf16, swizzled ds_write into 128B-row halves ----
    {
        const float* src = upts + (size_t)(row0 + lr) * 128 + lcq * 32;
        float4 f[8];
#pragma unroll
        for (int q = 0; q < 8; ++q) f[q] = ((const float4*)src)[q];
        unsigned char* Ah = smem + (lcq >> 1) * 16384;
        const int cb = (lcq & 1) * 64;
#pragma unroll
        for (int q = 0; q < 4; ++q) {
            float4 fa = f[q * 2], fb = f[q * 2 + 1];
            short8 o;
            o[0] = (short)f2bf(fa.x); o[1] = (short)f2bf(fa.y);
            o[2] = (short)f2bf(fa.z); o[3] = (short)f2bf(fa.w);
            o[4] = (short)f2bf(fb.x); o[5] = (short)f2bf(fb.y);
            o[6] = (short)f2bf(fb.z); o[7] = (short)f2bf(fb.w);
            *(short8*)(Ah + lr * 128 + ((cb + q * 16) ^ ((lr & 7) << 4))) = o;
        }
    }
    __syncthreads();

    // ---- GEMM: K=128, 4 ks, 32 MFMA/wave ----
    f32x4 acc[4][2];
#pragma unroll
    for (int m = 0; m < 4; ++m)
#pragma unroll
        for (int n = 0; n < 2; ++n) {
            f32x4 z = {0.f, 0.f, 0.f, 0.f};
            acc[m][n] = z;
        }
#pragma unroll
    for (int ks = 0; ks < 4; ++ks) {
        const unsigned char* Al = smem + (ks >> 1) * 16384;
        const unsigned char* Bl = smem + 32768 + (ks >> 1) * 16384;
        const int bo = (ks & 1) * 64 + (l >> 4) * 16;
        short8 a[4], bq[2];
#pragma unroll
        for (int m = 0; m < 4; ++m) {
            const int r = wm * 64 + m * 16 + (l & 15);
            a[m] = *(const short8*)(Al + r * 128 + (bo ^ ((r & 7) << 4)));
        }
#pragma unroll
        for (int n = 0; n < 2; ++n) {
            const int r = wn * 32 + n * 16 + (l & 15);
            bq[n] = *(const short8*)(Bl + r * 128 + (bo ^ ((r & 7) << 4)));
        }
#pragma unroll
        for (int m = 0; m < 4; ++m)
#pragma unroll
            for (int n = 0; n < 2; ++n)
                acc[m][n] = __builtin_amdgcn_mfma_f32_16x16x32_bf16(
                    a[m], bq[n], acc[m][n], 0, 0, 0);
    }

    // ---- epilogue: stage bf16 acc -> LDS [128][136], coalesced write ----
    __syncthreads();                         // all LDS reads done
    {
        unsigned short* st = (unsigned short*)smem;
#pragma unroll
        for (int m = 0; m < 4; ++m)
#pragma unroll
            for (int n = 0; n < 2; ++n)
#pragma unroll
                for (int r = 0; r < 4; ++r) {
                    const int row = wm * 64 + m * 16 + (l >> 4) * 4 + r;
                    const int col = wn * 32 + n * 16 + (l & 15);
                    st[row * 136 + col] = f2bf(acc[m][n][r]);
                }
    }
    __syncthreads();
    {
        const int row = tid >> 2, cb = (tid & 3) * 32;
        const unsigned short* st = (const unsigned short*)smem;
        unsigned short* dst = Y0u + (size_t)(row0 + row) * 256 + nh * 128 + cb;
#pragma unroll
        for (int i = 0; i < 4; ++i)
            *(short8*)(dst + i * 8) = *(const short8*)(st + row * 136 + cb + i * 8);
    }
}

// ---------------------------------------------------------------------------
// KI: interp_y0: y0 = Y0u + sum_j w_j Z[idx_j]; stats0 into 8 replicas.
// All global accesses streaming/vectorized; Z gathers L2-resident (8.4MB).
// ---------------------------------------------------------------------------
__global__ __launch_bounds__(256) void interp_y0_kernel(
    const uint4* __restrict__ widx,
    const unsigned short* __restrict__ Z,
    const unsigned short* __restrict__ Y0u,
    unsigned short* __restrict__ Y0,
    float* __restrict__ statsR)              // [8][512]
{
    __shared__ int   sidx[64][3];
    __shared__ float sw[64][3];
    __shared__ float sst[4][512];

    const int tid = threadIdx.x;
    const int bid = blockIdx.x;
    const int b   = bid & 7;
    const int pn  = (bid >> 3) * 64;
    const int wv = tid >> 6, lane = tid & 63;

    if (tid < 64) {
        uint4 wq = widx[(size_t)b * NN + pn + tid];
        float w0 = __uint_as_float(wq.x);
        float w1 = __uint_as_float(wq.y);
        sidx[tid][0] = (int)(wq.z & 0xFFFFu);
        sidx[tid][1] = (int)(wq.z >> 16);
        sidx[tid][2] = (int)wq.w;
        sw[tid][0] = w0; sw[tid][1] = w1; sw[tid][2] = 1.0f - w0 - w1;
    }
    __syncthreads();

    float s1[4] = {0.f, 0.f, 0.f, 0.f}, s2[4] = {0.f, 0.f, 0.f, 0.f};
    const unsigned short* Zb = Z + (size_t)b * SS * 256;
    for (int p = wv; p < 64; p += 4) {
        const int j0 = sidx[p][0], j1 = sidx[p][1], j2 = sidx[p][2];
        const float w0 = sw[p][0], w1 = sw[p][1], w2 = sw[p][2];
        const size_t rb = ((size_t)b * NN + pn + p) * 256 + lane * 4;

        ushort4 z0 = *(const ushort4*)(Zb + (size_t)j0 * 256 + lane * 4);
        ushort4 z1 = *(const ushort4*)(Zb + (size_t)j1 * 256 + lane * 4);
        ushort4 z2 = *(const ushort4*)(Zb + (size_t)j2 * 256 + lane * 4);
        ushort4 u  = *(const ushort4*)(Y0u + rb);

        float f0 = bf2f(u.x) + fmaf(w2, bf2f(z2.x), fmaf(w1, bf2f(z1.x), w0 * bf2f(z0.x)));
        float f1 = bf2f(u.y) + fmaf(w2, bf2f(z2.y), fmaf(w1, bf2f(z1.y), w0 * bf2f(z0.y)));
        float f2v = bf2f(u.z) + fmaf(w2, bf2f(z2.z), fmaf(w1, bf2f(z1.z), w0 * bf2f(z0.z)));
        float f3 = bf2f(u.w) + fmaf(w2, bf2f(z2.w), fmaf(w1, bf2f(z1.w), w0 * bf2f(z0.w)));

        ushort4 o;
        o.x = f2bf(f0); o.y = f2bf(f1); o.z = f2bf(f2v); o.w = f2bf(f3);
        *(ushort4*)(Y0 + rb) = o;

        s1[0] += f0;  s2[0] += f0 * f0;
        s1[1] += f1;  s2[1] += f1 * f1;
        s1[2] += f2v; s2[2] += f2v * f2v;
        s1[3] += f3;  s2[3] += f3 * f3;
    }

    // per-wave partials: lane covers cols lane*4+j uniquely
#pragma unroll
    for (int j = 0; j < 4; ++j) {
        sst[wv][lane * 4 + j] = s1[j];
        sst[wv][256 + lane * 4 + j] = s2[j];
    }
    __syncthreads();
    {
        float v = sst[0][tid] + sst[1][tid] + sst[2][tid] + sst[3][tid];
        float q = sst[0][256 + tid] + sst[1][256 + tid] +
                  sst[2][256 + tid] + sst[3][256 + tid];
        atomicAdd(&statsR[b * 512 + tid], v);
        atomicAdd(&statsR[b * 512 + 256 + tid], q);
    }
}

// ---------------------------------------------------------------------------
// K4: GEMM2  y1 = relu(bn0(y0)) @ W1^T  (BN0 finalize sums 8 replicas)
// ---------------------------------------------------------------------------
#define G2_NT (K2DIM / BK)   // 4
__global__ __launch_bounds__(512, 4) void gemm2_kernel(
    const unsigned short* __restrict__ Y0,
    const unsigned short* __restrict__ Wb,
    const float* __restrict__ statsR,        // [8][512]
    const float* __restrict__ g0,
    const float* __restrict__ beta0,
    unsigned short* __restrict__ Y1,
    float* __restrict__ stats)
{
    __shared__ __align__(128) unsigned char smem[2 * 32768];
    __shared__ float sgm[K2DIM], sga[K2DIM];

    const int tid = threadIdx.x;
    const int l = tid & 63, w = tid >> 6;
    const int wm = w >> 2, wn = w & 3;
    const int row0 = blockIdx.x * 128;
    const int srow = l >> 3;
    const int sbo  = (l & 7) * 16;
    const int lr  = tid >> 2;
    const int lcq = tid & 3;

    f32x4 acc[4][2];
#pragma unroll
    for (int m = 0; m < 4; ++m)
#pragma unroll
        for (int n = 0; n < 2; ++n) {
            f32x4 z = {0.f, 0.f, 0.f, 0.f};
            acc[m][n] = z;
        }

    const unsigned char* Bb = (const unsigned char*)Wb;
    short8 areg0, areg1;

    auto issueA = [&](int t) {
        const unsigned short* src = Y0 + (size_t)(row0 + lr) * K2DIM + t * BK + lcq * 16;
        areg0 = *(const short8*)src;
        areg1 = *(const short8*)(src + 8);
    };
    auto stageB = [&](int buf, int t) {
        unsigned char* Bl = smem + buf * 32768 + 16384;
        const int k0b = t * (BK * 2);
#pragma unroll
        for (int i = 0; i < 2; ++i) {
            const int r = w * 16 + i * 8 + srow;
            gload_lds16(Bb + (size_t)r * (K2DIM * 2) + k0b + (sbo ^ ((r & 7) << 4)),
                        Bl + r * 128 + sbo);
        }
    };
    auto xformA = [&](int buf, int t) {
        unsigned char* Al = smem + buf * 32768;
        const int kb = t * BK + lcq * 16;
        short8 o0, o1;
#pragma unroll
        for (int j = 0; j < 8; ++j) {
            float f = bf2f((unsigned short)areg0[j]);
            f = fmaxf(fmaf(f, sgm[kb + j], sga[kb + j]), 0.f);
            o0[j] = (short)f2bf(f);
            float g = bf2f((unsigned short)areg1[j]);
            g = fmaxf(fmaf(g, sgm[kb + 8 + j], sga[kb + 8 + j]), 0.f);
            o1[j] = (short)f2bf(g);
        }
        const int bo = lcq * 32;
        *(short8*)(Al + lr * 128 + ((bo) ^ ((lr & 7) << 4))) = o0;
        *(short8*)(Al + lr * 128 + ((bo + 16) ^ ((lr & 7) << 4))) = o1;
    };
    auto compute = [&](int buf) {
        const unsigned char* Al = smem + buf * 32768;
        const unsigned char* Bl = Al + 16384;
#pragma unroll
        for (int ks = 0; ks < 2; ++ks) {
            const int bo = ks * 64 + (l >> 4) * 16;
            short8 a[4], bq[2];
#pragma unroll
            for (int m = 0; m < 4; ++m) {
                const int r = wm * 64 + m * 16 + (l & 15);
                a[m] = *(const short8*)(Al + r * 128 + (bo ^ ((r & 7) << 4)));
            }
#pragma unroll
            for (int n = 0; n < 2; ++n) {
                const int r = wn * 32 + n * 16 + (l & 15);
                bq[n] = *(const short8*)(Bl + r * 128 + (bo ^ ((r & 7) << 4)));
            }
#pragma unroll
            for (int m = 0; m < 4; ++m)
#pragma unroll
                for (int n = 0; n < 2; ++n)
                    acc[m][n] = __builtin_amdgcn_mfma_f32_16x16x32_bf16(
                        a[m], bq[n], acc[m][n], 0, 0, 0);
        }
    };

    if (tid < K2DIM) {
        float s = 0.f, q = 0.f;
#pragma unroll
        for (int r = 0; r < 8; ++r) {
            s += statsR[r * 512 + tid];
            q += statsR[r * 512 + 256 + tid];
        }
        const float inv = 1.0f / (float)M_TOT;
        float mean = s * inv;
        float var  = q * inv - mean * mean;
        float m = g0[tid] * rsqrtf(var + 1e-5f);
        sgm[tid] = m;
        sga[tid] = beta0[tid] - mean * m;
    }
    issueA(0);
    stageB(0, 0);
    __syncthreads();
    xformA(0, 0);
    __syncthreads();

#pragma unroll
    for (int t = 0; t < G2_NT; ++t) {
        const int cur = t & 1;
        if (t + 1 < G2_NT) { issueA(t + 1); stageB(cur ^ 1, t + 1); }
        compute(cur);
        if (t + 1 < G2_NT) xformA(cur ^ 1, t + 1);
        __syncthreads();
    }

    float s1[2] = {0.f, 0.f}, s2[2] = {0.f, 0.f};
#pragma unroll
    for (int m = 0; m < 4; ++m) {
        const int row = row0 + wm * 64 + m * 16 + (l >> 4) * 4;
#pragma unroll
        for (int n = 0; n < 2; ++n) {
            const int col = wn * 32 + n * 16 + (l & 15);
            f32x4 v = acc[m][n];
#pragma unroll
            for (int r = 0; r < 4; ++r) {
                float f = v[r];
                Y1[(size_t)(row + r) * N2DIM + col] = f2bf(f);
                s1[n] += f;
                s2[n] += f * f;
            }
        }
    }
#pragma unroll
    for (int n = 0; n < 2; ++n) {
        s1[n] += __shfl_xor(s1[n], 16, 64);
        s1[n] += __shfl_xor(s1[n], 32, 64);
        s2[n] += __shfl_xor(s2[n], 16, 64);
        s2[n] += __shfl_xor(s2[n], 32, 64);
    }
    if (l < 16) {
#pragma unroll
        for (int n = 0; n < 2; ++n) {
            const int col = wn * 32 + n * 16 + l;
            atomicAdd(&stats[col], s1[n]);
            atomicAdd(&stats[N2DIM + col], s2[n]);
        }
    }
}

// ---------------------------------------------------------------------------
// K6: out = relu(bn1(y1)), BN1 finalize inlined; y1 bf16 in, out f32.
// ---------------------------------------------------------------------------
__global__ __launch_bounds__(256) void bn_out_kernel(
    const unsigned short* __restrict__ Y1, const float* __restrict__ stats1,
    const float* __restrict__ g1, const float* __restrict__ beta1,
    float* __restrict__ out)
{
    __shared__ float sgm[N2DIM], sga[N2DIM];
    const int tid = threadIdx.x;
    if (tid < N2DIM) {
        const float inv = 1.0f / (float)M_TOT;
        float mean = stats1[tid] * inv;
        float var  = stats1[N2DIM + tid] * inv - mean * mean;
        float m = g1[tid] * rsqrtf(var + 1e-5f);
        sgm[tid] = m;
        sga[tid] = beta1[tid] - mean * m;
    }
    __syncthreads();

    const int total = M_TOT * N2DIM / 8;
    for (int i = blockIdx.x * 256 + tid; i < total; i += gridDim.x * 256) {
        short8 v = ((const short8*)Y1)[i];
        const int cg = (i & 15) * 8;
        float4 o1, o2;
        o1.x = fmaxf(fmaf(bf2f((unsigned short)v[0]), sgm[cg + 0], sga[cg + 0]), 0.f);
        o1.y = fmaxf(fmaf(bf2f((unsigned short)v[1]), sgm[cg + 1], sga[cg + 1]), 0.f);
        o1.z = fmaxf(fmaf(bf2f((unsigned short)v[2]), sgm[cg + 2], sga[cg + 2]), 0.f);
        o1.w = fmaxf(fmaf(bf2f((unsigned short)v[3]), sgm[cg + 3], sga[cg + 3]), 0.f);
        o2.x = fmaxf(fmaf(bf2f((unsigned short)v[4]), sgm[cg + 4], sga[cg + 4]), 0.f);
        o2.y = fmaxf(fmaf(bf2f((unsigned short)v[5]), sgm[cg + 5], sga[cg + 5]), 0.f);
        o2.z = fmaxf(fmaf(bf2f((unsigned short)v[6]), sgm[cg + 6], sga[cg + 6]), 0.f);
        o2.w = fmaxf(fmaf(bf2f((unsigned short)v[7]), sgm[cg + 7], sga[cg + 7]), 0.f);
        ((float4*)out)[i * 2]     = o1;
        ((float4*)out)[i * 2 + 1] = o2;
    }
}

// ---------------------------------------------------------------------------
// launch
// ---------------------------------------------------------------------------
extern "C" void kernel_launch(void* const* d_in, const int* in_sizes, int n_in,
                              void* d_out, int out_size, void* d_ws, size_t ws_size,
                              hipStream_t stream)
{
    const float* uxyz  = (const float*)d_in[0];
    const float* kxyz  = (const float*)d_in[1];
    const float* upts  = (const float*)d_in[2];
    const float* kpts  = (const float*)d_in[3];
    const float* W0    = (const float*)d_in[4];
    const float* g0    = (const float*)d_in[6];
    const float* beta0 = (const float*)d_in[7];
    const float* W1    = (const float*)d_in[8];
    const float* g1    = (const float*)d_in[10];
    const float* beta1 = (const float*)d_in[11];
    float* out = (float*)d_out;

    char* ws = (char*)d_ws;
    const size_t off_xz = 0;                 // Y0u bf16 [M][256] 33.5MB; y1 bf16 aliases after
    const size_t off_y0 = 33554432;          // Y0 bf16 [M][256]; grid structs + kpack alias
    const size_t off_z  = 67108864;          // Z bf16 [16384][256] 8.4MB
    const size_t off_w  = 75497472;          // weights + stats + widx

    unsigned short* Y0u  = (unsigned short*)(ws + off_xz);
    unsigned short* y1   = (unsigned short*)(ws + off_xz);        // aliases Y0u
    unsigned short* y0   = (unsigned short*)(ws + off_y0);
    // grid structs alias the y0 region (consumed before interp_y0 writes y0)
    float4* table    = (float4*)(ws + off_y0);                    // 512KB
    int*    cellcnt  = (int*)(ws + off_y0 + 524288);              // 4KB
    int*    nfail    = (int*)(ws + off_y0 + 528384);              // 4B
    int*    faillist = (int*)(ws + off_y0 + 532480);              // 256KB
    float4* kpack    = (float4*)(ws + off_y0 + 8388608);          // 256KB
    unsigned short* Zb   = (unsigned short*)(ws + off_z);
    unsigned short* wa   = (unsigned short*)(ws + off_w);
    unsigned short* wb   = (unsigned short*)(ws + off_w + 65536);
    unsigned short* wb1  = (unsigned short*)(ws + off_w + 196608);
    float* F = (float*)(ws + off_w + 262144);
    float* statsR = F;                // [8][512]
    float* stats1 = F + 4096;         // [256]
    uint4* widx = (uint4*)(ws + off_w + 262144 + 18432);          // 1MB

    cvt_w_kernel<<<384, 256, 0, stream>>>(W0, W1, kxyz, wa, wb, wb1, kpack,
                                          table, cellcnt, nfail, F);
    bin_scatter_kernel<<<64, 256, 0, stream>>>(kxyz, table, cellcnt);
    nn_grid_kernel<<<1024, 256, 0, stream>>>(uxyz, table, cellcnt, kpack,
                                             widx, faillist, nfail);
    nn_brute_kernel<<<256, 256, 0, stream>>>(uxyz, kpack, faillist, nfail, widx);
    zgemm_kernel<<<256, 512, 0, stream>>>(kpts, wb, Zb);
    gemm1u_kernel<<<1024, 512, 0, stream>>>(upts, wa, Y0u);
    interp_y0_kernel<<<1024, 256, 0, stream>>>(widx, Zb, Y0u, y0, statsR);
    gemm2_kernel<<<512, 512, 0, stream>>>(y0, wb1, statsR, g0, beta0, y1, stats1);
    bn_out_kernel<<<2048, 256, 0, stream>>>(y1, stats1, g1, beta1, out);
}

// Round 11
// 144.968 us; speedup vs baseline: 1.1231x; 1.0451x over previous
//
#include <hip/hip_runtime.h>
#include <hip/hip_bf16.h>

// ---------------------------------------------------------------------------
// PointNet Feature Propagation, MI355X (gfx950)
//   Algebra: y0 = upts@W0a^T + sum_j w_j * Z[idx_j],  Z = kpts@W0b^T
//   3-NN via 5^3 spatial grid (exact: top-5 + rescue + brute fail path).
//   KB:  bin_scatter
//   KM:  mid_kernel = {nn_grid | zgemm | gemm1u} co-dispatched (independent)
//   KF:  nn_brute
//   KI:  interp_y0   y0 = Y0u + interp(Z) + stats0 (8-replica)
//   K4:  gemm2 (BN0 finalize from replicas, BN0+ReLU fused A) -> y1 bf16
//   K6:  bn_out (BN1 finalize inline) -> out f32
// ---------------------------------------------------------------------------

typedef __attribute__((ext_vector_type(8))) short short8;
typedef __attribute__((ext_vector_type(4))) float f32x4;

#define BB 8
#define NN 8192
#define SS 2048
#define M_TOT (BB * NN)      // 65536 points
#define N1DIM 256
#define K2DIM 256
#define N2DIM 128
#define BK 64

#define GDIM 5
#define NCELL (GDIM * GDIM * GDIM)   // 125
#define SLOTS 32
#define CELLW 0.2f

#define KEY_MASK 0xFFFFF800u
#define IDX_MASK 0x7FFu

__device__ __forceinline__ unsigned short f2bf(float f) {
    unsigned int x = __float_as_uint(f);
    unsigned int r = x + 0x7fffu + ((x >> 16) & 1u);  // RNE
    return (unsigned short)(r >> 16);
}
__device__ __forceinline__ float bf2f(unsigned short u) {
    return __uint_as_float(((unsigned int)u) << 16);
}
__device__ __forceinline__ unsigned int med3_u32(unsigned int a, unsigned int b,
                                                 unsigned int c) {
    unsigned int r;
    asm("v_med3_u32 %0, %1, %2, %3" : "=v"(r) : "v"(a), "v"(b), "v"(c));
    return r;
}

// insert key into sorted ascending k[0..4]
__device__ __forceinline__ void ins5(unsigned int k[5], unsigned int key) {
    unsigned int n1 = med3_u32(k[0], k[1], key);
    unsigned int n2 = med3_u32(k[1], k[2], key);
    unsigned int n3 = med3_u32(k[2], k[3], key);
    unsigned int n4 = med3_u32(k[3], k[4], key);
    k[0] = min(k[0], key);
    k[1] = n1; k[2] = n2; k[3] = n3; k[4] = n4;
}

// exact-distance rescue of quantized top-5 -> widx write; returns exact d3.
__device__ __forceinline__ float rescue_write(
    const unsigned int k[5], float qx, float qy, float qz,
    const float4* __restrict__ kpB, uint4* __restrict__ widx, size_t pt)
{
    unsigned long long e[5];
#pragma unroll
    for (int i = 0; i < 5; ++i) {
        if ((k[i] & KEY_MASK) >= 0x7F800000u) {
            e[i] = 0xFFFFFFFFFFFFFFFFull;
        } else {
            unsigned int idx = k[i] & IDX_MASK;
            float4 c = kpB[idx];
            float dx = c.x - qx, dy = c.y - qy, dz = c.z - qz;
            float d = fmaf(dx, dx, fmaf(dy, dy, dz * dz));
            e[i] = ((unsigned long long)__float_as_uint(d) << 32) | idx;
        }
    }
#pragma unroll
    for (int i = 0; i < 3; ++i)
#pragma unroll
        for (int j = i + 1; j < 5; ++j)
            if (e[j] < e[i]) { unsigned long long t = e[i]; e[i] = e[j]; e[j] = t; }

    float d0 = __uint_as_float((unsigned int)(e[0] >> 32));
    float d1 = __uint_as_float((unsigned int)(e[1] >> 32));
    float d2 = __uint_as_float((unsigned int)(e[2] >> 32));
    float r0 = 1.0f / (d0 + 1e-8f);
    float r1 = 1.0f / (d1 + 1e-8f);
    float r2 = 1.0f / (d2 + 1e-8f);
    float rs = 1.0f / (r0 + r1 + r2);
    unsigned int i0 = (unsigned int)(e[0] & IDX_MASK);
    unsigned int i1 = (unsigned int)(e[1] & IDX_MASK);
    unsigned int i2 = (unsigned int)(e[2] & IDX_MASK);
    widx[pt] = make_uint4(__float_as_uint(r0 * rs), __float_as_uint(r1 * rs),
                          i0 | (i1 << 16), i2);
    return d2;
}

// async 16B global->LDS DMA (wave-uniform LDS base + lane*16).
__device__ __forceinline__ void gload_lds16(const void* g, void* lds) {
    __builtin_amdgcn_global_load_lds(
        (const __attribute__((address_space(1))) unsigned int*)g,
        (__attribute__((address_space(3))) unsigned int*)lds, 16, 0, 0);
}

// ---------------------------------------------------------------------------
// K0: weights cvt + kpack + grid-table fill + stats zero.
// ---------------------------------------------------------------------------
__global__ __launch_bounds__(256) void cvt_w_kernel(
    const float* __restrict__ W0, const float* __restrict__ W1,
    const float* __restrict__ kxyz,
    unsigned short* __restrict__ Wa, unsigned short* __restrict__ Wb,
    unsigned short* __restrict__ Wb1, float4* __restrict__ kpack,
    float4* __restrict__ table, int* __restrict__ cnt,
    int* __restrict__ nfail, float* __restrict__ statsF)
{
    int i = blockIdx.x * 256 + threadIdx.x;
    if (blockIdx.x == 0) {
        for (int j = threadIdx.x; j < 4608; j += 256) statsF[j] = 0.0f;
        if (threadIdx.x == 0) *nfail = 0;
    }
    if (i < BB * NCELL) cnt[i] = 0;
    if (i < BB * NCELL * SLOTS)
        table[i] = make_float4(1e30f, 1e30f, 1e30f, 0.0f);
    if (i < 256 * 384) {
        int o = i / 384, c = i - o * 384;
        unsigned short v = f2bf(W0[i]);
        if (c < 128) Wa[o * 128 + c] = v;
        else         Wb[o * 256 + (c - 128)] = v;
    }
    if (i < N2DIM * K2DIM) Wb1[i] = f2bf(W1[i]);
    if (i < BB * SS) {
        const float* p = kxyz + (size_t)i * 3;
        float px = p[0], py = p[1], pz = p[2];
        kpack[i] = make_float4(px, py, pz, fmaf(px, px, fmaf(py, py, pz * pz)));
    }
}

// ---------------------------------------------------------------------------
// KB: scatter known points into cell table.
// ---------------------------------------------------------------------------
__global__ __launch_bounds__(256) void bin_scatter_kernel(
    const float* __restrict__ kxyz, float4* __restrict__ table,
    int* __restrict__ cnt)
{
    int i = blockIdx.x * 256 + threadIdx.x;
    if (i >= BB * SS) return;
    int b = i >> 11, s = i & 2047;
    const float* p = kxyz + (size_t)i * 3;
    float x = p[0], y = p[1], z = p[2];
    int cx = min((int)(x * GDIM), GDIM - 1);
    int cy = min((int)(y * GDIM), GDIM - 1);
    int cz = min((int)(z * GDIM), GDIM - 1);
    int cell = (cz * GDIM + cy) * GDIM + cx;
    int slot = atomicAdd(&cnt[b * NCELL + cell], 1);
    if (slot < SLOTS)
        table[((size_t)(b * NCELL + cell)) * SLOTS + slot] =
            make_float4(x, y, z, __int_as_float(s));
}

// ---------------------------------------------------------------------------
// KM: fused middle stage. Blocks [0,512): nn_grid (512thr = 128 queries);
// [512,768): zgemm; [768,1792): gemm1u. Bodies are R10-proven, re-indexed.
// ---------------------------------------------------------------------------
#define NNB 512
#define ZB  256
#define G1B 1024
__global__ __launch_bounds__(512, 4) void mid_kernel(
    const float* __restrict__ uxyz, const float4* __restrict__ table,
    const int* __restrict__ cnt, const float4* __restrict__ kpack,
    uint4* __restrict__ widx, int* __restrict__ fail_list,
    int* __restrict__ nfail,
    const float* __restrict__ kpts, const unsigned short* __restrict__ Wb,
    unsigned short* __restrict__ Z,
    const float* __restrict__ upts, const unsigned short* __restrict__ Wa,
    unsigned short* __restrict__ Y0u)
{
    __shared__ __align__(128) unsigned char smem[65536];
    const int bid = blockIdx.x;
    const int tid = threadIdx.x;

    if (bid < NNB) {
        // ---------------- nn_grid ----------------
        const int t  = bid * 512 + tid;
        const int qd = t & 3;
        const size_t pt = (size_t)(t >> 2);
        const int b = (int)(pt >> 13);

        const float* up = uxyz + pt * 3;
        const float qx = up[0], qy = up[1], qz = up[2];

        const int cx = min((int)(qx * GDIM), GDIM - 1);
        const int cy = min((int)(qy * GDIM), GDIM - 1);
        const int cz = min((int)(qz * GDIM), GDIM - 1);
        const float fx = qx * GDIM - cx, fy = qy * GDIM - cy, fz = qz * GDIM - cz;
        int ox = cx - (fx <= 0.5f ? 1 : 0); ox = max(0, min(ox, GDIM - 2));
        int oy = cy - (fy <= 0.5f ? 1 : 0); oy = max(0, min(oy, GDIM - 2));
        int oz = cz - (fz <= 0.5f ? 1 : 0); oz = max(0, min(oz, GDIM - 2));

        const float4* tb = table + (size_t)b * NCELL * SLOTS;
        const int* cb = cnt + b * NCELL;

        unsigned int k[5] = {0xFFFFFFFFu, 0xFFFFFFFFu, 0xFFFFFFFFu,
                             0xFFFFFFFFu, 0xFFFFFFFFu};
        int ovf = 0;
#pragma unroll
        for (int jj = 0; jj < 2; ++jj) {
            const int j = qd * 2 + jj;
            const int dx = j & 1, dy = (j >> 1) & 1, dz = j >> 2;
            const int cell = ((oz + dz) * GDIM + (oy + dy)) * GDIM + (ox + dx);
            ovf |= (cb[cell] > SLOTS) ? 1 : 0;
            const float4* cp = tb + (size_t)cell * SLOTS;
#pragma unroll 8
            for (int s = 0; s < SLOTS; ++s) {
                float4 c = cp[s];
                float ddx = c.x - qx, ddy = c.y - qy, ddz = c.z - qz;
                float d = fmaf(ddx, ddx, fmaf(ddy, ddy, ddz * ddz));
                unsigned int key = (__float_as_uint(d) & KEY_MASK) |
                                   (unsigned int)__float_as_int(c.w);
                ins5(k, key);
            }
        }

#pragma unroll
        for (int m = 1; m <= 2; m <<= 1) {
            unsigned int f0 = (unsigned int)__shfl_xor((int)k[0], m);
            unsigned int f1 = (unsigned int)__shfl_xor((int)k[1], m);
            unsigned int f2 = (unsigned int)__shfl_xor((int)k[2], m);
            unsigned int f3 = (unsigned int)__shfl_xor((int)k[3], m);
            unsigned int f4 = (unsigned int)__shfl_xor((int)k[4], m);
            ovf |= __shfl_xor(ovf, m);
            ins5(k, f0); ins5(k, f1); ins5(k, f2); ins5(k, f3); ins5(k, f4);
        }

        if (qd != 0) return;

        float d3 = rescue_write(k, qx, qy, qz, kpack + (size_t)b * SS, widx, pt);

        float lx = ox * CELLW, rx = (ox + 2) * CELLW;
        float ly = oy * CELLW, ry = (oy + 2) * CELLW;
        float lz = oz * CELLW, rz = (oz + 2) * CELLW;
        float covx = fminf(ox == 0 ? 1e30f : qx - lx, ox == GDIM - 2 ? 1e30f : rx - qx);
        float covy = fminf(oy == 0 ? 1e30f : qy - ly, oy == GDIM - 2 ? 1e30f : ry - qy);
        float covz = fminf(oz == 0 ? 1e30f : qz - lz, oz == GDIM - 2 ? 1e30f : rz - qz);
        float g = fminf(covx, fminf(covy, covz));

        if (ovf || !(d3 <= g * g)) {
            int pos = atomicAdd(nfail, 1);
            fail_list[pos] = (int)pt;
        }
        return;
    }

    const int l = tid & 63, w = tid >> 6;
    const int wm = w >> 2, wn = w & 3;
    const int srow = l >> 3, sbo = (l & 7) * 16;
    const int lr = tid >> 2, lcq = tid & 3;

    if (bid < NNB + ZB) {
        // ---------------- zgemm ----------------
        const int vb = bid - NNB;
        const int mt = vb >> 1, nh = vb & 1;
        const int row0 = mt * 128;

        f32x4 acc[4][2];
#pragma unroll
        for (int m = 0; m < 4; ++m)
#pragma unroll
            for (int n = 0; n < 2; ++n) {
                f32x4 z = {0.f, 0.f, 0.f, 0.f};
                acc[m][n] = z;
            }

        const unsigned char* Bb = (const unsigned char*)Wb + (size_t)nh * 128 * 512;
        float4 af0, af1, af2, af3;

        auto issueA = [&](int t) {
            const float* src = kpts + (size_t)(row0 + lr) * 256 + t * 64 + lcq * 16;
            af0 = ((const float4*)src)[0];
            af1 = ((const float4*)src)[1];
            af2 = ((const float4*)src)[2];
            af3 = ((const float4*)src)[3];
        };
        auto stageB = [&](int buf, int t) {
            unsigned char* Bl = smem + buf * 32768 + 16384;
#pragma unroll
            for (int i = 0; i < 2; ++i) {
                const int r = w * 16 + i * 8 + srow;
                gload_lds16(Bb + (size_t)r * 512 + t * 128 + (sbo ^ ((r & 7) << 4)),
                            Bl + r * 128 + sbo);
            }
        };
        auto xformA = [&](int buf) {
            unsigned char* Al = smem + buf * 32768;
            short8 o0, o1;
            o0[0] = (short)f2bf(af0.x); o0[1] = (short)f2bf(af0.y);
            o0[2] = (short)f2bf(af0.z); o0[3] = (short)f2bf(af0.w);
            o0[4] = (short)f2bf(af1.x); o0[5] = (short)f2bf(af1.y);
            o0[6] = (short)f2bf(af1.z); o0[7] = (short)f2bf(af1.w);
            o1[0] = (short)f2bf(af2.x); o1[1] = (short)f2bf(af2.y);
            o1[2] = (short)f2bf(af2.z); o1[3] = (short)f2bf(af2.w);
            o1[4] = (short)f2bf(af3.x); o1[5] = (short)f2bf(af3.y);
            o1[6] = (short)f2bf(af3.z); o1[7] = (short)f2bf(af3.w);
            const int bo = lcq * 32;
            *(short8*)(Al + lr * 128 + ((bo) ^ ((lr & 7) << 4))) = o0;
            *(short8*)(Al + lr * 128 + ((bo + 16) ^ ((lr & 7) << 4))) = o1;
        };
        auto compute = [&](int buf) {
            const unsigned char* Al = smem + buf * 32768;
            const unsigned char* Bl = Al + 16384;
#pragma unroll
            for (int ks = 0; ks < 2; ++ks) {
                const int bo = ks * 64 + (l >> 4) * 16;
                short8 a[4], bq[2];
#pragma unroll
                for (int m = 0; m < 4; ++m) {
                    const int r = wm * 64 + m * 16 + (l & 15);
                    a[m] = *(const short8*)(Al + r * 128 + (bo ^ ((r & 7) << 4)));
                }
#pragma unroll
                for (int n = 0; n < 2; ++n) {
                    const int r = wn * 32 + n * 16 + (l & 15);
                    bq[n] = *(const short8*)(Bl + r * 128 + (bo ^ ((r & 7) << 4)));
                }
#pragma unroll
                for (int m = 0; m < 4; ++m)
#pragma unroll
                    for (int n = 0; n < 2; ++n)
                        acc[m][n] = __builtin_amdgcn_mfma_f32_16x16x32_bf16(
                            a[m], bq[n], acc[m][n], 0, 0, 0);
            }
        };

        issueA(0);
        stageB(0, 0);
        xformA(0);
        __syncthreads();
#pragma unroll
        for (int t = 0; t < 4; ++t) {
            const int cur = t & 1;
            if (t + 1 < 4) { issueA(t + 1); stageB(cur ^ 1, t + 1); }
            compute(cur);
            if (t + 1 < 4) xformA(cur ^ 1);
            __syncthreads();
        }

#pragma unroll
        for (int m = 0; m < 4; ++m) {
            const int row = row0 + wm * 64 + m * 16 + (l >> 4) * 4;
#pragma unroll
            for (int n = 0; n < 2; ++n) {
                const int col = nh * 128 + wn * 32 + n * 16 + (l & 15);
                f32x4 v = acc[m][n];
#pragma unroll
                for (int r = 0; r < 4; ++r)
                    Z[(size_t)(row + r) * 256 + col] = f2bf(v[r]);
            }
        }
        return;
    }

    // ---------------- gemm1u ----------------
    {
        const int vb = bid - (NNB + ZB);
        const int mt = vb >> 1, nh = vb & 1;
        const int row0 = mt * 128;

        // stage B: Wa[nh*128 + r], rows 256B split into 2x128B halves
        {
            const unsigned char* Bb = (const unsigned char*)Wa + (size_t)nh * 128 * 256;
#pragma unroll
            for (int h = 0; h < 2; ++h)
#pragma unroll
                for (int i = 0; i < 2; ++i) {
                    const int r = w * 16 + i * 8 + srow;
                    gload_lds16(Bb + (size_t)r * 256 + h * 128 + (sbo ^ ((r & 7) << 4)),
                                smem + 32768 + h * 16384 + r * 128 + sbo);
                }
        }
        // stage A: upts f32 -> bf16, swizzled ds_write
        {
            const float* src = upts + (size_t)(row0 + lr) * 128 + lcq * 32;
            float4 f[8];
#pragma unroll
            for (int q = 0; q < 8; ++q) f[q] = ((const float4*)src)[q];
            unsigned char* Ah = smem + (lcq >> 1) * 16384;
            const int cb = (lcq & 1) * 64;
#pragma unroll
            for (int q = 0; q < 4; ++q) {
                float4 fa = f[q * 2], fb = f[q * 2 + 1];
                short8 o;
                o[0] = (short)f2bf(fa.x); o[1] = (short)f2bf(fa.y);
                o[2] = (short)f2bf(fa.z); o[3] = (short)f2bf(fa.w);
                o[4] = (short)f2bf(fb.x); o[5] = (short)f2bf(fb.y);
                o[6] = (short)f2bf(fb.z); o[7] = (short)f2bf(fb.w);
                *(short8*)(Ah + lr * 128 + ((cb + q * 16) ^ ((lr & 7) << 4))) = o;
            }
        }
        __syncthreads();

        f32x4 acc[4][2];
#pragma unroll
        for (int m = 0; m < 4; ++m)
#pragma unroll
            for (int n = 0; n < 2; ++n) {
                f32x4 z = {0.f, 0.f, 0.f, 0.f};
                acc[m][n] = z;
            }
#pragma unroll
        for (int ks = 0; ks < 4; ++ks) {
            const unsigned char* Al = smem + (ks >> 1) * 16384;
            const unsigned char* Bl = smem + 32768 + (ks >> 1) * 16384;
            const int bo = (ks & 1) * 64 + (l >> 4) * 16;
            short8 a[4], bq[2];
#pragma unroll
            for (int m = 0; m < 4; ++m) {
                const int r = wm * 64 + m * 16 + (l & 15);
                a[m] = *(const short8*)(Al + r * 128 + (bo ^ ((r & 7) << 4)));
            }
#pragma unroll
            for (int n = 0; n < 2; ++n) {
                const int r = wn * 32 + n * 16 + (l & 15);
                bq[n] = *(const short8*)(Bl + r * 128 + (bo ^ ((r & 7) << 4)));
            }
#pragma unroll
            for (int m = 0; m < 4; ++m)
#pragma unroll
                for (int n = 0; n < 2; ++n)
                    acc[m][n] = __builtin_amdgcn_mfma_f32_16x16x32_bf16(
                        a[m], bq[n], acc[m][n], 0, 0, 0);
        }

        // epilogue: stage bf16 acc -> LDS [128][136], coalesced write
        __syncthreads();
        {
            unsigned short* st = (unsigned short*)smem;
#pragma unroll
            for (int m = 0; m < 4; ++m)
#pragma unroll
                for (int n = 0; n < 2; ++n)
#pragma unroll
                    for (int r = 0; r < 4; ++r) {
                        const int row = wm * 64 + m * 16 + (l >> 4) * 4 + r;
                        const int col = wn * 32 + n * 16 + (l & 15);
                        st[row * 136 + col] = f2bf(acc[m][n][r]);
                    }
        }
        __syncthreads();
        {
            const int row = tid >> 2, cb = (tid & 3) * 32;
            const unsigned short* st = (const unsigned short*)smem;
            unsigned short* dst = Y0u + (size_t)(row0 + row) * 256 + nh * 128 + cb;
#pragma unroll
            for (int i = 0; i < 4; ++i)
                *(short8*)(dst + i * 8) = *(const short8*)(st + row * 136 + cb + i * 8);
        }
    }
}

// ---------------------------------------------------------------------------
// KF: brute-force fallback, one wave per failed query.
// ---------------------------------------------------------------------------
__global__ __launch_bounds__(256) void nn_brute_kernel(
    const float* __restrict__ uxyz, const float4* __restrict__ kpack,
    const int* __restrict__ fail_list, const int* __restrict__ nfail,
    uint4* __restrict__ widx)
{
    const int l = threadIdx.x & 63;
    const int wv = (blockIdx.x * 256 + threadIdx.x) >> 6;
    const int nw = (gridDim.x * 256) >> 6;
    const int n = *nfail;

    for (int q = wv; q < n; q += nw) {
        const size_t pt = (size_t)fail_list[q];
        const int b = (int)(pt >> 13);
        const float* up = uxyz + pt * 3;
        const float qx = up[0], qy = up[1], qz = up[2];
        const float4* kp = kpack + (size_t)b * SS;

        unsigned int k[5] = {0xFFFFFFFFu, 0xFFFFFFFFu, 0xFFFFFFFFu,
                             0xFFFFFFFFu, 0xFFFFFFFFu};
#pragma unroll 4
        for (int s = l; s < SS; s += 64) {
            float4 c = kp[s];
            float ddx = c.x - qx, ddy = c.y - qy, ddz = c.z - qz;
            float d = fmaf(ddx, ddx, fmaf(ddy, ddy, ddz * ddz));
            unsigned int key = (__float_as_uint(d) & KEY_MASK) | (unsigned int)s;
            ins5(k, key);
        }
#pragma unroll
        for (int m = 1; m <= 32; m <<= 1) {
            unsigned int f0 = (unsigned int)__shfl_xor((int)k[0], m);
            unsigned int f1 = (unsigned int)__shfl_xor((int)k[1], m);
            unsigned int f2 = (unsigned int)__shfl_xor((int)k[2], m);
            unsigned int f3 = (unsigned int)__shfl_xor((int)k[3], m);
            unsigned int f4 = (unsigned int)__shfl_xor((int)k[4], m);
            ins5(k, f0); ins5(k, f1); ins5(k, f2); ins5(k, f3); ins5(k, f4);
        }
        if (l == 0)
            rescue_write(k, qx, qy, qz, kp, widx, pt);
    }
}

// ---------------------------------------------------------------------------
// KI: interp_y0: y0 = Y0u + sum_j w_j Z[idx_j]; stats0 into 8 replicas.
// ---------------------------------------------------------------------------
__global__ __launch_bounds__(256) void interp_y0_kernel(
    const uint4* __restrict__ widx,
    const unsigned short* __restrict__ Z,
    const unsigned short* __restrict__ Y0u,
    unsigned short* __restrict__ Y0,
    float* __restrict__ statsR)              // [8][512]
{
    __shared__ int   sidx[64][3];
    __shared__ float sw[64][3];
    __shared__ float sst[4][512];

    const int tid = threadIdx.x;
    const int bid = blockIdx.x;
    const int b   = bid & 7;
    const int pn  = (bid >> 3) * 64;
    const int wv = tid >> 6, lane = tid & 63;

    if (tid < 64) {
        uint4 wq = widx[(size_t)b * NN + pn + tid];
        float w0 = __uint_as_float(wq.x);
        float w1 = __uint_as_float(wq.y);
        sidx[tid][0] = (int)(wq.z & 0xFFFFu);
        sidx[tid][1] = (int)(wq.z >> 16);
        sidx[tid][2] = (int)wq.w;
        sw[tid][0] = w0; sw[tid][1] = w1; sw[tid][2] = 1.0f - w0 - w1;
    }
    __syncthreads();

    float s1[4] = {0.f, 0.f, 0.f, 0.f}, s2[4] = {0.f, 0.f, 0.f, 0.f};
    const unsigned short* Zb = Z + (size_t)b * SS * 256;
    for (int p = wv; p < 64; p += 4) {
        const int j0 = sidx[p][0], j1 = sidx[p][1], j2 = sidx[p][2];
        const float w0 = sw[p][0], w1 = sw[p][1], w2 = sw[p][2];
        const size_t rb = ((size_t)b * NN + pn + p) * 256 + lane * 4;

        ushort4 z0 = *(const ushort4*)(Zb + (size_t)j0 * 256 + lane * 4);
        ushort4 z1 = *(const ushort4*)(Zb + (size_t)j1 * 256 + lane * 4);
        ushort4 z2 = *(const ushort4*)(Zb + (size_t)j2 * 256 + lane * 4);
        ushort4 u  = *(const ushort4*)(Y0u + rb);

        float f0 = bf2f(u.x) + fmaf(w2, bf2f(z2.x), fmaf(w1, bf2f(z1.x), w0 * bf2f(z0.x)));
        float f1 = bf2f(u.y) + fmaf(w2, bf2f(z2.y), fmaf(w1, bf2f(z1.y), w0 * bf2f(z0.y)));
        float f2v = bf2f(u.z) + fmaf(w2, bf2f(z2.z), fmaf(w1, bf2f(z1.z), w0 * bf2f(z0.z)));
        float f3 = bf2f(u.w) + fmaf(w2, bf2f(z2.w), fmaf(w1, bf2f(z1.w), w0 * bf2f(z0.w)));

        ushort4 o;
        o.x = f2bf(f0); o.y = f2bf(f1); o.z = f2bf(f2v); o.w = f2bf(f3);
        *(ushort4*)(Y0 + rb) = o;

        s1[0] += f0;  s2[0] += f0 * f0;
        s1[1] += f1;  s2[1] += f1 * f1;
        s1[2] += f2v; s2[2] += f2v * f2v;
        s1[3] += f3;  s2[3] += f3 * f3;
    }

#pragma unroll
    for (int j = 0; j < 4; ++j) {
        sst[wv][lane * 4 + j] = s1[j];
        sst[wv][256 + lane * 4 + j] = s2[j];
    }
    __syncthreads();
    {
        float v = sst[0][tid] + sst[1][tid] + sst[2][tid] + sst[3][tid];
        float q = sst[0][256 + tid] + sst[1][256 + tid] +
                  sst[2][256 + tid] + sst[3][256 + tid];
        atomicAdd(&statsR[b * 512 + tid], v);
        atomicAdd(&statsR[b * 512 + 256 + tid], q);
    }
}

// ---------------------------------------------------------------------------
// K4: GEMM2  y1 = relu(bn0(y0)) @ W1^T  (BN0 finalize sums 8 replicas)
// ---------------------------------------------------------------------------
#define G2_NT (K2DIM / BK)   // 4
__global__ __launch_bounds__(512, 4) void gemm2_kernel(
    const unsigned short* __restrict__ Y0,
    const unsigned short* __restrict__ Wb,
    const float* __restrict__ statsR,        // [8][512]
    const float* __restrict__ g0,
    const float* __restrict__ beta0,
    unsigned short* __restrict__ Y1,
    float* __restrict__ stats)
{
    __shared__ __align__(128) unsigned char smem[2 * 32768];
    __shared__ float sgm[K2DIM], sga[K2DIM];

    const int tid = threadIdx.x;
    const int l = tid & 63, w = tid >> 6;
    const int wm = w >> 2, wn = w & 3;
    const int row0 = blockIdx.x * 128;
    const int srow = l >> 3;
    const int sbo  = (l & 7) * 16;
    const int lr  = tid >> 2;
    const int lcq = tid & 3;

    f32x4 acc[4][2];
#pragma unroll
    for (int m = 0; m < 4; ++m)
#pragma unroll
        for (int n = 0; n < 2; ++n) {
            f32x4 z = {0.f, 0.f, 0.f, 0.f};
            acc[m][n] = z;
        }

    const unsigned char* Bb = (const unsigned char*)Wb;
    short8 areg0, areg1;

    auto issueA = [&](int t) {
        const unsigned short* src = Y0 + (size_t)(row0 + lr) * K2DIM + t * BK + lcq * 16;
        areg0 = *(const short8*)src;
        areg1 = *(const short8*)(src + 8);
    };
    auto stageB = [&](int buf, int t) {
        unsigned char* Bl = smem + buf * 32768 + 16384;
        const int k0b = t * (BK * 2);
#pragma unroll
        for (int i = 0; i < 2; ++i) {
            const int r = w * 16 + i * 8 + srow;
            gload_lds16(Bb + (size_t)r * (K2DIM * 2) + k0b + (sbo ^ ((r & 7) << 4)),
                        Bl + r * 128 + sbo);
        }
    };
    auto xformA = [&](int buf, int t) {
        unsigned char* Al = smem + buf * 32768;
        const int kb = t * BK + lcq * 16;
        short8 o0, o1;
#pragma unroll
        for (int j = 0; j < 8; ++j) {
            float f = bf2f((unsigned short)areg0[j]);
            f = fmaxf(fmaf(f, sgm[kb + j], sga[kb + j]), 0.f);
            o0[j] = (short)f2bf(f);
            float g = bf2f((unsigned short)areg1[j]);
            g = fmaxf(fmaf(g, sgm[kb + 8 + j], sga[kb + 8 + j]), 0.f);
            o1[j] = (short)f2bf(g);
        }
        const int bo = lcq * 32;
        *(short8*)(Al + lr * 128 + ((bo) ^ ((lr & 7) << 4))) = o0;
        *(short8*)(Al + lr * 128 + ((bo + 16) ^ ((lr & 7) << 4))) = o1;
    };
    auto compute = [&](int buf) {
        const unsigned char* Al = smem + buf * 32768;
        const unsigned char* Bl = Al + 16384;
#pragma unroll
        for (int ks = 0; ks < 2; ++ks) {
            const int bo = ks * 64 + (l >> 4) * 16;
            short8 a[4], bq[2];
#pragma unroll
            for (int m = 0; m < 4; ++m) {
                const int r = wm * 64 + m * 16 + (l & 15);
                a[m] = *(const short8*)(Al + r * 128 + (bo ^ ((r & 7) << 4)));
            }
#pragma unroll
            for (int n = 0; n < 2; ++n) {
                const int r = wn * 32 + n * 16 + (l & 15);
                bq[n] = *(const short8*)(Bl + r * 128 + (bo ^ ((r & 7) << 4)));
            }
#pragma unroll
            for (int m = 0; m < 4; ++m)
#pragma unroll
                for (int n = 0; n < 2; ++n)
                    acc[m][n] = __builtin_amdgcn_mfma_f32_16x16x32_bf16(
                        a[m], bq[n], acc[m][n], 0, 0, 0);
        }
    };

    if (tid < K2DIM) {
        float s = 0.f, q = 0.f;
#pragma unroll
        for (int r = 0; r < 8; ++r) {
            s += statsR[r * 512 + tid];
            q += statsR[r * 512 + 256 + tid];
        }
        const float inv = 1.0f / (float)M_TOT;
        float mean = s * inv;
        float var  = q * inv - mean * mean;
        float m = g0[tid] * rsqrtf(var + 1e-5f);
        sgm[tid] = m;
        sga[tid] = beta0[tid] - mean * m;
    }
    issueA(0);
    stageB(0, 0);
    __syncthreads();
    xformA(0, 0);
    __syncthreads();

#pragma unroll
    for (int t = 0; t < G2_NT; ++t) {
        const int cur = t & 1;
        if (t + 1 < G2_NT) { issueA(t + 1); stageB(cur ^ 1, t + 1); }
        compute(cur);
        if (t + 1 < G2_NT) xformA(cur ^ 1, t + 1);
        __syncthreads();
    }

    float s1[2] = {0.f, 0.f}, s2[2] = {0.f, 0.f};
#pragma unroll
    for (int m = 0; m < 4; ++m) {
        const int row = row0 + wm * 64 + m * 16 + (l >> 4) * 4;
#pragma unroll
        for (int n = 0; n < 2; ++n) {
            const int col = wn * 32 + n * 16 + (l & 15);
            f32x4 v = acc[m][n];
#pragma unroll
            for (int r = 0; r < 4; ++r) {
                float f = v[r];
                Y1[(size_t)(row + r) * N2DIM + col] = f2bf(f);
                s1[n] += f;
                s2[n] += f * f;
            }
        }
    }
#pragma unroll
    for (int n = 0; n < 2; ++n) {
        s1[n] += __shfl_xor(s1[n], 16, 64);
        s1[n] += __shfl_xor(s1[n], 32, 64);
        s2[n] += __shfl_xor(s2[n], 16, 64);
        s2[n] += __shfl_xor(s2[n], 32, 64);
    }
    if (l < 16) {
#pragma unroll
        for (int n = 0; n < 2; ++n) {
            const int col = wn * 32 + n * 16 + l;
            atomicAdd(&stats[col], s1[n]);
            atomicAdd(&stats[N2DIM + col], s2[n]);
        }
    }
}

// ---------------------------------------------------------------------------
// K6: out = relu(bn1(y1)), BN1 finalize inlined; y1 bf16 in, out f32.
// ---------------------------------------------------------------------------
__global__ __launch_bounds__(256) void bn_out_kernel(
    const unsigned short* __restrict__ Y1, const float* __restrict__ stats1,
    const float* __restrict__ g1, const float* __restrict__ beta1,
    float* __restrict__ out)
{
    __shared__ float sgm[N2DIM], sga[N2DIM];
    const int tid = threadIdx.x;
    if (tid < N2DIM) {
        const float inv = 1.0f / (float)M_TOT;
        float mean = stats1[tid] * inv;
        float var  = stats1[N2DIM + tid] * inv - mean * mean;
        float m = g1[tid] * rsqrtf(var + 1e-5f);
        sgm[tid] = m;
        sga[tid] = beta1[tid] - mean * m;
    }
    __syncthreads();

    const int total = M_TOT * N2DIM / 8;
    for (int i = blockIdx.x * 256 + tid; i < total; i += gridDim.x * 256) {
        short8 v = ((const short8*)Y1)[i];
        const int cg = (i & 15) * 8;
        float4 o1, o2;
        o1.x = fmaxf(fmaf(bf2f((unsigned short)v[0]), sgm[cg + 0], sga[cg + 0]), 0.f);
        o1.y = fmaxf(fmaf(bf2f((unsigned short)v[1]), sgm[cg + 1], sga[cg + 1]), 0.f);
        o1.z = fmaxf(fmaf(bf2f((unsigned short)v[2]), sgm[cg + 2], sga[cg + 2]), 0.f);
        o1.w = fmaxf(fmaf(bf2f((unsigned short)v[3]), sgm[cg + 3], sga[cg + 3]), 0.f);
        o2.x = fmaxf(fmaf(bf2f((unsigned short)v[4]), sgm[cg + 4], sga[cg + 4]), 0.f);
        o2.y = fmaxf(fmaf(bf2f((unsigned short)v[5]), sgm[cg + 5], sga[cg + 5]), 0.f);
        o2.z = fmaxf(fmaf(bf2f((unsigned short)v[6]), sgm[cg + 6], sga[cg + 6]), 0.f);
        o2.w = fmaxf(fmaf(bf2f((unsigned short)v[7]), sgm[cg + 7], sga[cg + 7]), 0.f);
        ((float4*)out)[i * 2]     = o1;
        ((float4*)out)[i * 2 + 1] = o2;
    }
}

// ---------------------------------------------------------------------------
// launch
// ---------------------------------------------------------------------------
extern "C" void kernel_launch(void* const* d_in, const int* in_sizes, int n_in,
                              void* d_out, int out_size, void* d_ws, size_t ws_size,
                              hipStream_t stream)
{
    const float* uxyz  = (const float*)d_in[0];
    const float* kxyz  = (const float*)d_in[1];
    const float* upts  = (const float*)d_in[2];
    const float* kpts  = (const float*)d_in[3];
    const float* W0    = (const float*)d_in[4];
    const float* g0    = (const float*)d_in[6];
    const float* beta0 = (const float*)d_in[7];
    const float* W1    = (const float*)d_in[8];
    const float* g1    = (const float*)d_in[10];
    const float* beta1 = (const float*)d_in[11];
    float* out = (float*)d_out;

    char* ws = (char*)d_ws;
    const size_t off_xz = 0;                 // Y0u bf16 [M][256] 33.5MB; y1 bf16 aliases after
    const size_t off_y0 = 33554432;          // Y0 bf16 [M][256]; grid structs + kpack alias
    const size_t off_z  = 67108864;          // Z bf16 [16384][256] 8.4MB
    const size_t off_w  = 75497472;          // weights + stats + widx

    unsigned short* Y0u  = (unsigned short*)(ws + off_xz);
    unsigned short* y1   = (unsigned short*)(ws + off_xz);        // aliases Y0u
    unsigned short* y0   = (unsigned short*)(ws + off_y0);
    // grid structs alias the y0 region (consumed before interp_y0 writes y0)
    float4* table    = (float4*)(ws + off_y0);                    // 512KB
    int*    cellcnt  = (int*)(ws + off_y0 + 524288);              // 4KB
    int*    nfail    = (int*)(ws + off_y0 + 528384);              // 4B
    int*    faillist = (int*)(ws + off_y0 + 532480);              // 256KB
    float4* kpack    = (float4*)(ws + off_y0 + 8388608);          // 256KB
    unsigned short* Zb   = (unsigned short*)(ws + off_z);
    unsigned short* wa   = (unsigned short*)(ws + off_w);
    unsigned short* wb   = (unsigned short*)(ws + off_w + 65536);
    unsigned short* wb1  = (unsigned short*)(ws + off_w + 196608);
    float* F = (float*)(ws + off_w + 262144);
    float* statsR = F;                // [8][512]
    float* stats1 = F + 4096;         // [256]
    uint4* widx = (uint4*)(ws + off_w + 262144 + 18432);          // 1MB

    cvt_w_kernel<<<384, 256, 0, stream>>>(W0, W1, kxyz, wa, wb, wb1, kpack,
                                          table, cellcnt, nfail, F);
    bin_scatter_kernel<<<64, 256, 0, stream>>>(kxyz, table, cellcnt);
    mid_kernel<<<NNB + ZB + G1B, 512, 0, stream>>>(
        uxyz, table, cellcnt, kpack, widx, faillist, nfail,
        kpts, wb, Zb, upts, wa, Y0u);
    nn_brute_kernel<<<64, 256, 0, stream>>>(uxyz, kpack, faillist, nfail, widx);
    interp_y0_kernel<<<1024, 256, 0, stream>>>(widx, Zb, Y0u, y0, statsR);
    gemm2_kernel<<<512, 512, 0, stream>>>(y0, wb1, statsR, g0, beta0, y1, stats1);
    bn_out_kernel<<<2048, 256, 0, stream>>>(y1, stats1, g1, beta1, out);
}